// Round 1
// baseline (829.917 us; speedup 1.0000x reference)
//
#include <hip/hip_runtime.h>
#include <hip/hip_bf16.h>
#include <math.h>

#define NN   100000
#define EE   1600000
#define ETOT (NN + EE)
#define IND  128
#define HD   128    // HEADS*HID
#define OD   40
#define NEG  0.2f
#define BNEPS 1e-5f

__device__ __forceinline__ float lrelu(float x) { return x > 0.f ? x : NEG * x; }

// ---------------- GEMM0: h0[N,128] = x[N,128] @ W0[128,128] ----------------
__global__ __launch_bounds__(256) void gemm0_kernel(const float* __restrict__ x,
                                                    const float* __restrict__ W0,
                                                    float* __restrict__ h0) {
  __shared__ float xT[32][68];    // transposed x tile, padded
  __shared__ float Ws[32][128];
  int t = threadIdx.x;
  int rowbase = blockIdx.x * 64;
  int tx = t & 31, ty = t >> 5;   // tx: col-quad 0..31, ty: row-oct 0..7
  float acc[8][4];
#pragma unroll
  for (int i = 0; i < 8; i++)
#pragma unroll
    for (int j = 0; j < 4; j++) acc[i][j] = 0.f;

  for (int kt = 0; kt < 128; kt += 32) {
    // stage x transposed: 64 rows x 32 k
    {
      int row = t >> 3;   // 0..31
      int kq  = t & 7;    // k quad
#pragma unroll
      for (int rep = 0; rep < 2; rep++) {
        int r  = rowbase + row + rep * 32;
        int rc = r < NN ? r : NN - 1;
        float4 v = *(const float4*)&x[(size_t)rc * 128 + kt + kq * 4];
        xT[kq * 4 + 0][row + rep * 32] = v.x;
        xT[kq * 4 + 1][row + rep * 32] = v.y;
        xT[kq * 4 + 2][row + rep * 32] = v.z;
        xT[kq * 4 + 3][row + rep * 32] = v.w;
      }
    }
    // stage W tile: 32 k x 128 cols
    {
      int c4  = t & 31;
      int kk0 = t >> 5;
#pragma unroll
      for (int rep = 0; rep < 4; rep++) {
        int kk = kk0 + rep * 8;
        float4 v = *(const float4*)&W0[(size_t)(kt + kk) * 128 + c4 * 4];
        *(float4*)&Ws[kk][c4 * 4] = v;
      }
    }
    __syncthreads();
#pragma unroll
    for (int k = 0; k < 32; k++) {
      float4 b  = *(const float4*)&Ws[k][tx * 4];
      float4 a0 = *(const float4*)&xT[k][ty * 8];
      float4 a1 = *(const float4*)&xT[k][ty * 8 + 4];
      float av[8] = {a0.x, a0.y, a0.z, a0.w, a1.x, a1.y, a1.z, a1.w};
      float bv[4] = {b.x, b.y, b.z, b.w};
#pragma unroll
      for (int i = 0; i < 8; i++)
#pragma unroll
        for (int j = 0; j < 4; j++) acc[i][j] += av[i] * bv[j];
    }
    __syncthreads();
  }
#pragma unroll
  for (int i = 0; i < 8; i++) {
    int r = rowbase + ty * 8 + i;
    if (r < NN) {
      float4 v = make_float4(acc[i][0], acc[i][1], acc[i][2], acc[i][3]);
      *(float4*)&h0[(size_t)r * 128 + tx * 4] = v;
    }
  }
}

// ---------------- per-node attention logits, layer 0 ----------------
__global__ __launch_bounds__(256) void alphas0_kernel(const float* __restrict__ h0,
                                                      const float* __restrict__ a_src0,
                                                      const float* __restrict__ a_dst0,
                                                      float* __restrict__ asrc0,
                                                      float* __restrict__ adst0) {
  int t = threadIdx.x;
  int lane = t & 63, wv = t >> 6;
  int n = blockIdx.x * 4 + wv;
  if (n >= NN) return;
  float v1 = h0[(size_t)n * 128 + lane];
  float v2 = h0[(size_t)n * 128 + 64 + lane];
  float s1 = v1 * a_src0[lane],      d1 = v1 * a_dst0[lane];
  float s2 = v2 * a_src0[64 + lane], d2 = v2 * a_dst0[64 + lane];
#pragma unroll
  for (int m = 1; m < 32; m <<= 1) {
    s1 += __shfl_xor(s1, m); d1 += __shfl_xor(d1, m);
    s2 += __shfl_xor(s2, m); d2 += __shfl_xor(d2, m);
  }
  if ((lane & 31) == 0) {
    int hb = lane >> 5;  // 0 or 1
    asrc0[n * 4 + hb] = s1;     adst0[n * 4 + hb] = d1;
    asrc0[n * 4 + 2 + hb] = s2; adst0[n * 4 + 2 + hb] = d2;
  }
}

// ---------------- CSR build ----------------
__global__ void deg_kernel(const int* __restrict__ ei, int* __restrict__ deg) {
  int i = blockIdx.x * blockDim.x + threadIdx.x;
  if (i >= ETOT) return;
  int dst = (i < EE) ? ei[EE + i] : (i - EE);
  atomicAdd(&deg[dst], 1);
}

__global__ __launch_bounds__(256) void scanA_kernel(const int* __restrict__ deg,
                                                    int* __restrict__ scanned,
                                                    int* __restrict__ blocksums) {
  __shared__ int s[256];
  int t = threadIdx.x;
  int i = blockIdx.x * 256 + t;
  int v = (i < NN) ? deg[i] : 0;
  s[t] = v;
  __syncthreads();
  for (int off = 1; off < 256; off <<= 1) {
    int add = (t >= off) ? s[t - off] : 0;
    __syncthreads();
    s[t] += add;
    __syncthreads();
  }
  if (i < NN) scanned[i] = s[t];
  if (t == 255) blocksums[blockIdx.x] = s[255];
}

__global__ __launch_bounds__(512) void scanB_kernel(int* __restrict__ blocksums, int NB) {
  __shared__ int s[512];
  int t = threadIdx.x;
  int v = (t < NB) ? blocksums[t] : 0;
  s[t] = v;
  __syncthreads();
  for (int off = 1; off < 512; off <<= 1) {
    int add = (t >= off) ? s[t - off] : 0;
    __syncthreads();
    s[t] += add;
    __syncthreads();
  }
  if (t < NB) blocksums[t] = s[t] - v;  // exclusive block offset
}

__global__ __launch_bounds__(256) void scanC_kernel(const int* __restrict__ scanned,
                                                    const int* __restrict__ deg,
                                                    const int* __restrict__ blocksums,
                                                    int* __restrict__ rowptr) {
  int i = blockIdx.x * 256 + threadIdx.x;
  if (i < NN) rowptr[i] = blocksums[blockIdx.x] + scanned[i] - deg[i];
  if (i == 0) rowptr[NN] = ETOT;
}

__global__ void scatter_kernel(const int* __restrict__ ei, const int* __restrict__ rowptr,
                               int* __restrict__ cursor, int* __restrict__ csr_src) {
  int i = blockIdx.x * blockDim.x + threadIdx.x;
  if (i >= ETOT) return;
  int src, dst;
  if (i < EE) { src = ei[i]; dst = ei[EE + i]; }
  else        { src = dst = i - EE; }
  int pos = atomicAdd(&cursor[dst], 1);
  csr_src[rowptr[dst] + pos] = src;
}

// ---------------- layer-0 softmax + aggregate: one wave per node ----------------
__global__ __launch_bounds__(256) void agg0_kernel(const int* __restrict__ csr_src,
                                                   const int* __restrict__ rowptr,
                                                   const float* __restrict__ asrc0,
                                                   const float* __restrict__ adst0,
                                                   const float* __restrict__ h0,
                                                   const float* __restrict__ b0,
                                                   float* __restrict__ agg0) {
  int t = threadIdx.x;
  int lane = t & 63, wv = t >> 6;
  int n = blockIdx.x * 4 + wv;
  if (n >= NN) return;
  int start = rowptr[n], end = rowptr[n + 1];
  float ad0 = adst0[n * 4 + 0], ad1 = adst0[n * 4 + 1];
  float ad2 = adst0[n * 4 + 2], ad3 = adst0[n * 4 + 3];

  // phase 1: per-head max over incoming edges
  float m0 = -INFINITY, m1 = -INFINITY, m2 = -INFINITY, m3 = -INFINITY;
  for (int j = start + lane; j < end; j += 64) {
    int s = csr_src[j];
    float4 as = *(const float4*)&asrc0[s * 4];
    m0 = fmaxf(m0, lrelu(as.x + ad0));
    m1 = fmaxf(m1, lrelu(as.y + ad1));
    m2 = fmaxf(m2, lrelu(as.z + ad2));
    m3 = fmaxf(m3, lrelu(as.w + ad3));
  }
#pragma unroll
  for (int mk = 1; mk < 64; mk <<= 1) {
    m0 = fmaxf(m0, __shfl_xor(m0, mk));
    m1 = fmaxf(m1, __shfl_xor(m1, mk));
    m2 = fmaxf(m2, __shfl_xor(m2, mk));
    m3 = fmaxf(m3, __shfl_xor(m3, mk));
  }
  // phase 2: denominator
  float d0 = 0.f, d1 = 0.f, d2 = 0.f, d3 = 0.f;
  for (int j = start + lane; j < end; j += 64) {
    int s = csr_src[j];
    float4 as = *(const float4*)&asrc0[s * 4];
    d0 += expf(lrelu(as.x + ad0) - m0);
    d1 += expf(lrelu(as.y + ad1) - m1);
    d2 += expf(lrelu(as.z + ad2) - m2);
    d3 += expf(lrelu(as.w + ad3) - m3);
  }
#pragma unroll
  for (int mk = 1; mk < 64; mk <<= 1) {
    d0 += __shfl_xor(d0, mk);
    d1 += __shfl_xor(d1, mk);
    d2 += __shfl_xor(d2, mk);
    d3 += __shfl_xor(d3, mk);
  }
  float rd0 = 1.f / d0, rd1 = 1.f / d1, rd2 = 1.f / d2, rd3 = 1.f / d3;

  // phase 3: weighted aggregate; lane owns channels lane and lane+64
  int c1 = lane, c2 = lane + 64;
  bool lo = lane < 32;
  float mh1 = lo ? m0 : m1, mh2 = lo ? m2 : m3;
  float rh1 = lo ? rd0 : rd1, rh2 = lo ? rd2 : rd3;
  float ah1 = lo ? ad0 : ad1, ah2 = lo ? ad2 : ad3;
  float acc1 = 0.f, acc2 = 0.f;
  for (int j = start; j < end; j++) {
    int s = csr_src[j];
    const float* asp = &asrc0[s * 4];
    float a1v = lo ? asp[0] : asp[1];
    float a2v = lo ? asp[2] : asp[3];
    float w1 = expf(lrelu(a1v + ah1) - mh1) * rh1;
    float w2 = expf(lrelu(a2v + ah2) - mh2) * rh2;
    acc1 += w1 * h0[(size_t)s * 128 + c1];
    acc2 += w2 * h0[(size_t)s * 128 + c2];
  }
  agg0[(size_t)n * 128 + c1] = acc1 + b0[c1];
  agg0[(size_t)n * 128 + c2] = acc2 + b0[c2];
}

// ---------------- BatchNorm stats / finalize / apply+ELU ----------------
__global__ __launch_bounds__(256) void bnstats_kernel(const float* __restrict__ agg0,
                                                      float* __restrict__ bnsum,
                                                      float* __restrict__ bnsq) {
  int t = threadIdx.x;
  int c = t & 127;
  int g = blockIdx.x * 2 + (t >> 7);
  float s = 0.f, q = 0.f;
  for (int r = g; r < NN; r += 1024) {
    float v = agg0[(size_t)r * 128 + c];
    s += v;
    q += v * v;
  }
  __shared__ float ls[256], lq[256];
  ls[t] = s; lq[t] = q;
  __syncthreads();
  if (t < 128) {
    s = ls[t] + ls[t + 128];
    q = lq[t] + lq[t + 128];
    atomicAdd(&bnsum[c], s);
    atomicAdd(&bnsq[c], q);
  }
}

__global__ void bnfinal_kernel(const float* __restrict__ bnsum, const float* __restrict__ bnsq,
                               const float* __restrict__ gamma, const float* __restrict__ beta,
                               float* __restrict__ bnscale, float* __restrict__ bnshift) {
  int c = threadIdx.x;  // 128 threads
  float mu = bnsum[c] / (float)NN;
  float var = bnsq[c] / (float)NN - mu * mu;
  float sc = gamma[c] / sqrtf(var + BNEPS);
  bnscale[c] = sc;
  bnshift[c] = beta[c] - mu * sc;
}

__global__ void bnapply_kernel(float* __restrict__ a, const float* __restrict__ sc,
                               const float* __restrict__ sh) {
  size_t total4 = (size_t)NN * HD / 4;
  for (size_t i4 = blockIdx.x * blockDim.x + threadIdx.x; i4 < total4;
       i4 += (size_t)gridDim.x * blockDim.x) {
    float4 v = ((float4*)a)[i4];
    int c = (int)((i4 * 4) & 127);
    float y0 = v.x * sc[c + 0] + sh[c + 0];
    float y1 = v.y * sc[c + 1] + sh[c + 1];
    float y2 = v.z * sc[c + 2] + sh[c + 2];
    float y3 = v.w * sc[c + 3] + sh[c + 3];
    v.x = y0 > 0.f ? y0 : expm1f(y0);
    v.y = y1 > 0.f ? y1 : expm1f(y1);
    v.z = y2 > 0.f ? y2 : expm1f(y2);
    v.w = y3 > 0.f ? y3 : expm1f(y3);
    ((float4*)a)[i4] = v;
  }
}

// ---------------- GEMM1 + fused alpha1: h1[N,40] = in2 @ W1 ----------------
__global__ __launch_bounds__(256) void gemm1_kernel(const float* __restrict__ in2,
                                                    const float* __restrict__ W1,
                                                    const float* __restrict__ a_src1,
                                                    const float* __restrict__ a_dst1,
                                                    float* __restrict__ h1,
                                                    float* __restrict__ asrc1,
                                                    float* __restrict__ adst1) {
  __shared__ float W1s[128 * 40];
  int t = threadIdx.x;
  for (int i = t; i < 128 * 40; i += 256) W1s[i] = W1[i];
  __syncthreads();
  int lane = t & 63, wv = t >> 6;
  int r = blockIdx.x * 4 + wv;
  if (r >= NN) return;
  int c = lane;
  float acc = 0.f;
  if (c < 40) {
    for (int k = 0; k < 128; k += 4) {
      float4 xv = *(const float4*)&in2[(size_t)r * 128 + k];
      acc += xv.x * W1s[(k + 0) * 40 + c];
      acc += xv.y * W1s[(k + 1) * 40 + c];
      acc += xv.z * W1s[(k + 2) * 40 + c];
      acc += xv.w * W1s[(k + 3) * 40 + c];
    }
  }
  float ps = (c < 40) ? acc * a_src1[c] : 0.f;
  float pd = (c < 40) ? acc * a_dst1[c] : 0.f;
#pragma unroll
  for (int m = 1; m < 64; m <<= 1) {
    ps += __shfl_xor(ps, m);
    pd += __shfl_xor(pd, m);
  }
  if (lane == 0) { asrc1[r] = ps; adst1[r] = pd; }
  if (c < 40) h1[(size_t)r * 40 + c] = acc;
}

// ---------------- layer-1 softmax + aggregate ----------------
__global__ __launch_bounds__(256) void agg1_kernel(const int* __restrict__ csr_src,
                                                   const int* __restrict__ rowptr,
                                                   const float* __restrict__ asrc1,
                                                   const float* __restrict__ adst1,
                                                   const float* __restrict__ h1,
                                                   const float* __restrict__ b1,
                                                   float* __restrict__ out) {
  int t = threadIdx.x;
  int lane = t & 63, wv = t >> 6;
  int n = blockIdx.x * 4 + wv;
  if (n >= NN) return;
  int start = rowptr[n], end = rowptr[n + 1];
  float ad = adst1[n];
  float m = -INFINITY;
  for (int j = start + lane; j < end; j += 64)
    m = fmaxf(m, lrelu(asrc1[csr_src[j]] + ad));
#pragma unroll
  for (int mk = 1; mk < 64; mk <<= 1) m = fmaxf(m, __shfl_xor(m, mk));
  float d = 0.f;
  for (int j = start + lane; j < end; j += 64)
    d += expf(lrelu(asrc1[csr_src[j]] + ad) - m);
#pragma unroll
  for (int mk = 1; mk < 64; mk <<= 1) d += __shfl_xor(d, mk);
  float rd = 1.f / d;
  float acc = 0.f;
  for (int j = start; j < end; j++) {
    int s = csr_src[j];
    float w = expf(lrelu(asrc1[s] + ad) - m) * rd;
    if (lane < 40) acc += w * h1[(size_t)s * 40 + lane];
  }
  if (lane < 40) out[(size_t)n * 40 + lane] = acc + b1[lane];
}

// ---------------- host launch ----------------
extern "C" void kernel_launch(void* const* d_in, const int* in_sizes, int n_in,
                              void* d_out, int out_size, void* d_ws, size_t ws_size,
                              hipStream_t stream) {
  const float* x       = (const float*)d_in[0];
  const int*   ei      = (const int*)d_in[1];
  const float* W0      = (const float*)d_in[2];
  const float* a_src0  = (const float*)d_in[3];
  const float* a_dst0  = (const float*)d_in[4];
  const float* b0      = (const float*)d_in[5];
  const float* gamma0  = (const float*)d_in[6];
  const float* beta0   = (const float*)d_in[7];
  const float* W1      = (const float*)d_in[8];
  const float* a_src1  = (const float*)d_in[9];
  const float* a_dst1  = (const float*)d_in[10];
  const float* b1      = (const float*)d_in[11];
  float* out = (float*)d_out;

  // workspace bump allocator (256B aligned)
  char* ws = (char*)d_ws;
  size_t off = 0;
  auto alloc = [&](size_t bytes) {
    void* p = ws + off;
    off += (bytes + 255) & ~(size_t)255;
    return p;
  };
  float* h0     = (float*)alloc((size_t)NN * 128 * 4);
  float* agg0   = (float*)alloc((size_t)NN * 128 * 4);
  float* h1     = (float*)alloc((size_t)NN * 40 * 4);
  float* asrc0  = (float*)alloc((size_t)NN * 4 * 4);
  float* adst0  = (float*)alloc((size_t)NN * 4 * 4);
  float* asrc1  = (float*)alloc((size_t)NN * 4);
  float* adst1  = (float*)alloc((size_t)NN * 4);
  int*   deg    = (int*)alloc((size_t)NN * 4);       // zeroed below (contiguous w/ next 3)
  int*   cursor = (int*)alloc((size_t)NN * 4);
  float* bnsum  = (float*)alloc(128 * 4);
  float* bnsq   = (float*)alloc(128 * 4);
  float* bnscale= (float*)alloc(128 * 4);
  float* bnshift= (float*)alloc(128 * 4);
  int*   rowptr = (int*)alloc((size_t)(NN + 1) * 4);
  int*   scanned= (int*)alloc((size_t)NN * 4);
  int*   csr    = (int*)alloc((size_t)ETOT * 4);
  int*   bsums  = (int*)alloc(512 * 4);
  (void)ws_size; (void)in_sizes; (void)n_in; (void)out_size;

  // zero deg..bnsq (contiguous region)
  size_t zbytes = (char*)(bnsq + 128) - (char*)deg;
  hipMemsetAsync(deg, 0, zbytes, stream);

  const int NB = (NN + 255) / 256;                 // 391 scan blocks
  const int egrid = (ETOT + 255) / 256;

  gemm0_kernel<<<(NN + 63) / 64, 256, 0, stream>>>(x, W0, h0);
  alphas0_kernel<<<(NN + 3) / 4, 256, 0, stream>>>(h0, a_src0, a_dst0, asrc0, adst0);
  deg_kernel<<<egrid, 256, 0, stream>>>(ei, deg);
  scanA_kernel<<<NB, 256, 0, stream>>>(deg, scanned, bsums);
  scanB_kernel<<<1, 512, 0, stream>>>(bsums, NB);
  scanC_kernel<<<NB, 256, 0, stream>>>(scanned, deg, bsums, rowptr);
  scatter_kernel<<<egrid, 256, 0, stream>>>(ei, rowptr, cursor, csr);
  agg0_kernel<<<(NN + 3) / 4, 256, 0, stream>>>(csr, rowptr, asrc0, adst0, h0, b0, agg0);
  bnstats_kernel<<<512, 256, 0, stream>>>(agg0, bnsum, bnsq);
  bnfinal_kernel<<<1, 128, 0, stream>>>(bnsum, bnsq, gamma0, beta0, bnscale, bnshift);
  bnapply_kernel<<<2048, 256, 0, stream>>>(agg0, bnscale, bnshift);
  gemm1_kernel<<<(NN + 3) / 4, 256, 0, stream>>>(agg0, W1, a_src1, a_dst1, h1, asrc1, adst1);
  agg1_kernel<<<(NN + 3) / 4, 256, 0, stream>>>(csr, rowptr, asrc1, adst1, h1, b1, out);
}

// Round 2
// 588.047 us; speedup vs baseline: 1.4113x; 1.4113x over previous
//
#include <hip/hip_runtime.h>
#include <hip/hip_bf16.h>
#include <math.h>

#define NN   100000
#define EE   1600000
#define ETOT (NN + EE)
#define IND  128
#define HD   128    // HEADS*HID
#define OD   40
#define NEG  0.2f
#define BNEPS 1e-5f

__device__ __forceinline__ float lrelu(float x) { return x > 0.f ? x : NEG * x; }

// ---- GEMM0: h0[N,128] = x[N,128] @ W0[128,128], fused per-node alpha logits ----
__global__ __launch_bounds__(256) void gemm0_kernel(const float* __restrict__ x,
                                                    const float* __restrict__ W0,
                                                    const float* __restrict__ a_src0,
                                                    const float* __restrict__ a_dst0,
                                                    float* __restrict__ h0,
                                                    float* __restrict__ asrc0,
                                                    float* __restrict__ adst0) {
  __shared__ float xT[32][68];    // transposed x tile, padded
  __shared__ float Ws[32][128];
  int t = threadIdx.x;
  int rowbase = blockIdx.x * 64;
  int tx = t & 31, ty = t >> 5;   // tx: col-quad 0..31, ty: row-oct 0..7
  float acc[8][4];
#pragma unroll
  for (int i = 0; i < 8; i++)
#pragma unroll
    for (int j = 0; j < 4; j++) acc[i][j] = 0.f;

  for (int kt = 0; kt < 128; kt += 32) {
    {
      int row = t >> 3;   // 0..31
      int kq  = t & 7;    // k quad
#pragma unroll
      for (int rep = 0; rep < 2; rep++) {
        int r  = rowbase + row + rep * 32;
        int rc = r < NN ? r : NN - 1;
        float4 v = *(const float4*)&x[(size_t)rc * 128 + kt + kq * 4];
        xT[kq * 4 + 0][row + rep * 32] = v.x;
        xT[kq * 4 + 1][row + rep * 32] = v.y;
        xT[kq * 4 + 2][row + rep * 32] = v.z;
        xT[kq * 4 + 3][row + rep * 32] = v.w;
      }
    }
    {
      int c4  = t & 31;
      int kk0 = t >> 5;
#pragma unroll
      for (int rep = 0; rep < 4; rep++) {
        int kk = kk0 + rep * 8;
        float4 v = *(const float4*)&W0[(size_t)(kt + kk) * 128 + c4 * 4];
        *(float4*)&Ws[kk][c4 * 4] = v;
      }
    }
    __syncthreads();
#pragma unroll
    for (int k = 0; k < 32; k++) {
      float4 b  = *(const float4*)&Ws[k][tx * 4];
      float4 a0 = *(const float4*)&xT[k][ty * 8];
      float4 a1 = *(const float4*)&xT[k][ty * 8 + 4];
      float av[8] = {a0.x, a0.y, a0.z, a0.w, a1.x, a1.y, a1.z, a1.w};
      float bv[4] = {b.x, b.y, b.z, b.w};
#pragma unroll
      for (int i = 0; i < 8; i++)
#pragma unroll
        for (int j = 0; j < 4; j++) acc[i][j] += av[i] * bv[j];
    }
    __syncthreads();
  }
  // write h0
#pragma unroll
  for (int i = 0; i < 8; i++) {
    int r = rowbase + ty * 8 + i;
    if (r < NN) {
      float4 v = make_float4(acc[i][0], acc[i][1], acc[i][2], acc[i][3]);
      *(float4*)&h0[(size_t)r * 128 + tx * 4] = v;
    }
  }
  // fused alpha logits: head = tx>>3; reduce over 8 consecutive lanes (one head = 32 cols)
  float4 asv = *(const float4*)&a_src0[tx * 4];
  float4 adv = *(const float4*)&a_dst0[tx * 4];
#pragma unroll
  for (int i = 0; i < 8; i++) {
    float ps = acc[i][0] * asv.x + acc[i][1] * asv.y + acc[i][2] * asv.z + acc[i][3] * asv.w;
    float pd = acc[i][0] * adv.x + acc[i][1] * adv.y + acc[i][2] * adv.z + acc[i][3] * adv.w;
#pragma unroll
    for (int mk = 1; mk < 8; mk <<= 1) { ps += __shfl_xor(ps, mk); pd += __shfl_xor(pd, mk); }
    int r = rowbase + ty * 8 + i;
    if ((tx & 7) == 0 && r < NN) {
      int head = tx >> 3;
      asrc0[r * 4 + head] = ps;
      adst0[r * 4 + head] = pd;
    }
  }
}

// ---------------- CSR build ----------------
__global__ void deg_kernel(const int* __restrict__ ei, int* __restrict__ deg) {
  int i = blockIdx.x * blockDim.x + threadIdx.x;
  if (i >= ETOT) return;
  int dst = (i < EE) ? ei[EE + i] : (i - EE);
  atomicAdd(&deg[dst], 1);
}

__global__ __launch_bounds__(256) void scanA_kernel(const int* __restrict__ deg,
                                                    int* __restrict__ scanned,
                                                    int* __restrict__ blocksums) {
  __shared__ int s[256];
  int t = threadIdx.x;
  int i = blockIdx.x * 256 + t;
  int v = (i < NN) ? deg[i] : 0;
  s[t] = v;
  __syncthreads();
  for (int off = 1; off < 256; off <<= 1) {
    int add = (t >= off) ? s[t - off] : 0;
    __syncthreads();
    s[t] += add;
    __syncthreads();
  }
  if (i < NN) scanned[i] = s[t];
  if (t == 255) blocksums[blockIdx.x] = s[255];
}

__global__ __launch_bounds__(512) void scanB_kernel(int* __restrict__ blocksums, int NB) {
  __shared__ int s[512];
  int t = threadIdx.x;
  int v = (t < NB) ? blocksums[t] : 0;
  s[t] = v;
  __syncthreads();
  for (int off = 1; off < 512; off <<= 1) {
    int add = (t >= off) ? s[t - off] : 0;
    __syncthreads();
    s[t] += add;
    __syncthreads();
  }
  if (t < NB) blocksums[t] = s[t] - v;  // exclusive block offset
}

__global__ __launch_bounds__(256) void scanC_kernel(const int* __restrict__ scanned,
                                                    const int* __restrict__ deg,
                                                    const int* __restrict__ blocksums,
                                                    int* __restrict__ rowptr) {
  int i = blockIdx.x * 256 + threadIdx.x;
  if (i < NN) rowptr[i] = blocksums[blockIdx.x] + scanned[i] - deg[i];
  if (i == 0) rowptr[NN] = ETOT;
}

__global__ void scatter_kernel(const int* __restrict__ ei, const int* __restrict__ rowptr,
                               int* __restrict__ cursor, int* __restrict__ csr_src) {
  int i = blockIdx.x * blockDim.x + threadIdx.x;
  if (i >= ETOT) return;
  int src, dst;
  if (i < EE) { src = ei[i]; dst = ei[EE + i]; }
  else        { src = dst = i - EE; }
  int pos = atomicAdd(&cursor[dst], 1);
  csr_src[rowptr[dst] + pos] = src;
}

// ---- layer-0 aggregate: one wave per node, single edge pass, LDS-staged weights ----
__global__ __launch_bounds__(256) void agg0_kernel(const int* __restrict__ csr_src,
                                                   const int* __restrict__ rowptr,
                                                   const float* __restrict__ asrc0,
                                                   const float* __restrict__ adst0,
                                                   const float* __restrict__ h0,
                                                   const float* __restrict__ b0,
                                                   float* __restrict__ agg0) {
  __shared__ float ws[4][4][72];   // [wave][head][edge] padded (banks differ per head)
  __shared__ int   ss[4][64];
  int t = threadIdx.x;
  int lane = t & 63, wv = t >> 6;
  int n = blockIdx.x * 4 + wv;
  if (n >= NN) return;
  int start = rowptr[n], end = rowptr[n + 1];
  float4 ad = *(const float4*)&adst0[(size_t)n * 4];
  int c = lane * 2;          // this lane owns channels c, c+1 (same head)
  int head = lane >> 4;
  float accx = 0.f, accy = 0.f;
  float d0 = 0.f, d1 = 0.f, d2 = 0.f, d3 = 0.f;

  for (int base = start; base < end; base += 64) {
    int cnt = min(64, end - base);
    if (lane < cnt) {
      int s = csr_src[base + lane];
      float4 as = *(const float4*)&asrc0[(size_t)s * 4];
      float w0 = __expf(lrelu(as.x + ad.x));
      float w1 = __expf(lrelu(as.y + ad.y));
      float w2 = __expf(lrelu(as.z + ad.z));
      float w3 = __expf(lrelu(as.w + ad.w));
      d0 += w0; d1 += w1; d2 += w2; d3 += w3;
      ss[wv][lane] = s;
      ws[wv][0][lane] = w0;
      ws[wv][1][lane] = w1;
      ws[wv][2][lane] = w2;
      ws[wv][3][lane] = w3;
    }
    __builtin_amdgcn_wave_barrier();
    for (int e = 0; e < cnt; e++) {
      int s = ss[wv][e];                 // broadcast
      float w = ws[wv][head][e];         // 4 distinct banks
      float2 hv = *(const float2*)&h0[(size_t)s * 128 + c];
      accx += w * hv.x;
      accy += w * hv.y;
    }
    __builtin_amdgcn_wave_barrier();
  }
#pragma unroll
  for (int mk = 1; mk < 64; mk <<= 1) {
    d0 += __shfl_xor(d0, mk);
    d1 += __shfl_xor(d1, mk);
    d2 += __shfl_xor(d2, mk);
    d3 += __shfl_xor(d3, mk);
  }
  float dh = head == 0 ? d0 : head == 1 ? d1 : head == 2 ? d2 : d3;
  float rd = 1.f / dh;
  float2 o;
  o.x = accx * rd + b0[c];
  o.y = accy * rd + b0[c + 1];
  *(float2*)&agg0[(size_t)n * 128 + c] = o;
}

// ---------------- BatchNorm stats / finalize / apply+ELU ----------------
__global__ __launch_bounds__(256) void bnstats_kernel(const float* __restrict__ agg0,
                                                      float* __restrict__ bnsum,
                                                      float* __restrict__ bnsq) {
  int t = threadIdx.x;
  int c = t & 127;
  int g = blockIdx.x * 2 + (t >> 7);
  float s = 0.f, q = 0.f;
  for (int r = g; r < NN; r += 1024) {
    float v = agg0[(size_t)r * 128 + c];
    s += v;
    q += v * v;
  }
  __shared__ float ls[256], lq[256];
  ls[t] = s; lq[t] = q;
  __syncthreads();
  if (t < 128) {
    s = ls[t] + ls[t + 128];
    q = lq[t] + lq[t + 128];
    atomicAdd(&bnsum[c], s);
    atomicAdd(&bnsq[c], q);
  }
}

__global__ void bnfinal_kernel(const float* __restrict__ bnsum, const float* __restrict__ bnsq,
                               const float* __restrict__ gamma, const float* __restrict__ beta,
                               float* __restrict__ bnscale, float* __restrict__ bnshift) {
  int c = threadIdx.x;  // 128 threads
  float mu = bnsum[c] / (float)NN;
  float var = bnsq[c] / (float)NN - mu * mu;
  float sc = gamma[c] / sqrtf(var + BNEPS);
  bnscale[c] = sc;
  bnshift[c] = beta[c] - mu * sc;
}

__global__ void bnapply_kernel(float* __restrict__ a, const float* __restrict__ sc,
                               const float* __restrict__ sh) {
  size_t total4 = (size_t)NN * HD / 4;
  for (size_t i4 = blockIdx.x * blockDim.x + threadIdx.x; i4 < total4;
       i4 += (size_t)gridDim.x * blockDim.x) {
    float4 v = ((float4*)a)[i4];
    int c = (int)((i4 * 4) & 127);
    float y0 = v.x * sc[c + 0] + sh[c + 0];
    float y1 = v.y * sc[c + 1] + sh[c + 1];
    float y2 = v.z * sc[c + 2] + sh[c + 2];
    float y3 = v.w * sc[c + 3] + sh[c + 3];
    v.x = y0 > 0.f ? y0 : expm1f(y0);
    v.y = y1 > 0.f ? y1 : expm1f(y1);
    v.z = y2 > 0.f ? y2 : expm1f(y2);
    v.w = y3 > 0.f ? y3 : expm1f(y3);
    ((float4*)a)[i4] = v;
  }
}

// ---------------- GEMM1 + fused alpha1: h1[N,40] = in2 @ W1 ----------------
__global__ __launch_bounds__(256) void gemm1_kernel(const float* __restrict__ in2,
                                                    const float* __restrict__ W1,
                                                    const float* __restrict__ a_src1,
                                                    const float* __restrict__ a_dst1,
                                                    float* __restrict__ h1,
                                                    float* __restrict__ asrc1,
                                                    float* __restrict__ adst1) {
  __shared__ float W1s[128 * 40];
  int t = threadIdx.x;
  for (int i = t; i < 128 * 40; i += 256) W1s[i] = W1[i];
  __syncthreads();
  int lane = t & 63, wv = t >> 6;
  int r = blockIdx.x * 4 + wv;
  if (r >= NN) return;
  int c = lane;
  float acc = 0.f;
  if (c < 40) {
    for (int k = 0; k < 128; k += 4) {
      float4 xv = *(const float4*)&in2[(size_t)r * 128 + k];
      acc += xv.x * W1s[(k + 0) * 40 + c];
      acc += xv.y * W1s[(k + 1) * 40 + c];
      acc += xv.z * W1s[(k + 2) * 40 + c];
      acc += xv.w * W1s[(k + 3) * 40 + c];
    }
  }
  float ps = (c < 40) ? acc * a_src1[c] : 0.f;
  float pd = (c < 40) ? acc * a_dst1[c] : 0.f;
#pragma unroll
  for (int m = 1; m < 64; m <<= 1) {
    ps += __shfl_xor(ps, m);
    pd += __shfl_xor(pd, m);
  }
  if (lane == 0) { asrc1[r] = ps; adst1[r] = pd; }
  if (c < 40) h1[(size_t)r * 40 + c] = acc;
}

// ---- layer-1 aggregate: one wave per node, single edge pass, LDS-staged weights ----
__global__ __launch_bounds__(256) void agg1_kernel(const int* __restrict__ csr_src,
                                                   const int* __restrict__ rowptr,
                                                   const float* __restrict__ asrc1,
                                                   const float* __restrict__ adst1,
                                                   const float* __restrict__ h1,
                                                   const float* __restrict__ b1,
                                                   float* __restrict__ out) {
  __shared__ float ws[4][64];
  __shared__ int   ss[4][64];
  int t = threadIdx.x;
  int lane = t & 63, wv = t >> 6;
  int n = blockIdx.x * 4 + wv;
  if (n >= NN) return;
  int start = rowptr[n], end = rowptr[n + 1];
  float ad = adst1[n];
  float dsum = 0.f, acc = 0.f;
  for (int base = start; base < end; base += 64) {
    int cnt = min(64, end - base);
    if (lane < cnt) {
      int s = csr_src[base + lane];
      float w = __expf(lrelu(asrc1[s] + ad));
      dsum += w;
      ss[wv][lane] = s;
      ws[wv][lane] = w;
    }
    __builtin_amdgcn_wave_barrier();
    if (lane < 40) {
      for (int e = 0; e < cnt; e++) {
        int s = ss[wv][e];
        float w = ws[wv][e];
        acc += w * h1[(size_t)s * 40 + lane];
      }
    }
    __builtin_amdgcn_wave_barrier();
  }
#pragma unroll
  for (int mk = 1; mk < 64; mk <<= 1) dsum += __shfl_xor(dsum, mk);
  float rd = 1.f / dsum;
  if (lane < 40) out[(size_t)n * 40 + lane] = acc * rd + b1[lane];
}

// ---------------- host launch ----------------
extern "C" void kernel_launch(void* const* d_in, const int* in_sizes, int n_in,
                              void* d_out, int out_size, void* d_ws, size_t ws_size,
                              hipStream_t stream) {
  const float* x       = (const float*)d_in[0];
  const int*   ei      = (const int*)d_in[1];
  const float* W0      = (const float*)d_in[2];
  const float* a_src0  = (const float*)d_in[3];
  const float* a_dst0  = (const float*)d_in[4];
  const float* b0      = (const float*)d_in[5];
  const float* gamma0  = (const float*)d_in[6];
  const float* beta0   = (const float*)d_in[7];
  const float* W1      = (const float*)d_in[8];
  const float* a_src1  = (const float*)d_in[9];
  const float* a_dst1  = (const float*)d_in[10];
  const float* b1      = (const float*)d_in[11];
  float* out = (float*)d_out;

  char* ws = (char*)d_ws;
  size_t off = 0;
  auto alloc = [&](size_t bytes) {
    void* p = ws + off;
    off += (bytes + 255) & ~(size_t)255;
    return p;
  };
  float* h0     = (float*)alloc((size_t)NN * 128 * 4);
  float* agg0   = (float*)alloc((size_t)NN * 128 * 4);
  float* h1     = (float*)alloc((size_t)NN * 40 * 4);
  float* asrc0  = (float*)alloc((size_t)NN * 4 * 4);
  float* adst0  = (float*)alloc((size_t)NN * 4 * 4);
  float* asrc1  = (float*)alloc((size_t)NN * 4);
  float* adst1  = (float*)alloc((size_t)NN * 4);
  int*   deg    = (int*)alloc((size_t)NN * 4);       // zeroed below (contiguous region)
  int*   cursor = (int*)alloc((size_t)NN * 4);
  float* bnsum  = (float*)alloc(128 * 4);
  float* bnsq   = (float*)alloc(128 * 4);
  float* bnscale= (float*)alloc(128 * 4);
  float* bnshift= (float*)alloc(128 * 4);
  int*   rowptr = (int*)alloc((size_t)(NN + 1) * 4);
  int*   scanned= (int*)alloc((size_t)NN * 4);
  int*   csr    = (int*)alloc((size_t)ETOT * 4);
  int*   bsums  = (int*)alloc(512 * 4);
  (void)ws_size; (void)in_sizes; (void)n_in; (void)out_size;

  size_t zbytes = (char*)(bnsq + 128) - (char*)deg;
  hipMemsetAsync(deg, 0, zbytes, stream);

  const int NB = (NN + 255) / 256;
  const int egrid = (ETOT + 255) / 256;

  gemm0_kernel<<<(NN + 63) / 64, 256, 0, stream>>>(x, W0, a_src0, a_dst0, h0, asrc0, adst0);
  deg_kernel<<<egrid, 256, 0, stream>>>(ei, deg);
  scanA_kernel<<<NB, 256, 0, stream>>>(deg, scanned, bsums);
  scanB_kernel<<<1, 512, 0, stream>>>(bsums, NB);
  scanC_kernel<<<NB, 256, 0, stream>>>(scanned, deg, bsums, rowptr);
  scatter_kernel<<<egrid, 256, 0, stream>>>(ei, rowptr, cursor, csr);
  agg0_kernel<<<(NN + 3) / 4, 256, 0, stream>>>(csr, rowptr, asrc0, adst0, h0, b0, agg0);
  bnstats_kernel<<<512, 256, 0, stream>>>(agg0, bnsum, bnsq);
  bnfinal_kernel<<<1, 128, 0, stream>>>(bnsum, bnsq, gamma0, beta0, bnscale, bnshift);
  bnapply_kernel<<<2048, 256, 0, stream>>>(agg0, bnscale, bnshift);
  gemm1_kernel<<<(NN + 3) / 4, 256, 0, stream>>>(agg0, W1, a_src1, a_dst1, h1, asrc1, adst1);
  agg1_kernel<<<(NN + 3) / 4, 256, 0, stream>>>(csr, rowptr, asrc1, adst1, h1, b1, out);
}

// Round 3
// 525.357 us; speedup vs baseline: 1.5797x; 1.1193x over previous
//
#include <hip/hip_runtime.h>
#include <hip/hip_bf16.h>
#include <math.h>

#define NN   100000
#define EE   1600000
#define ETOT (NN + EE)
#define IND  128
#define HD   128    // HEADS*HID
#define OD   40
#define NEG  0.2f
#define BNEPS 1e-5f

__device__ __forceinline__ float lrelu(float x) { return x > 0.f ? x : NEG * x; }

// pack two floats to bf16x2 (RNE)
__device__ __forceinline__ unsigned pack_bf16(float a, float b) {
  unsigned ua = __float_as_uint(a), ub = __float_as_uint(b);
  ua = (ua + 0x7fffu + ((ua >> 16) & 1u)) >> 16;
  ub = (ub + 0x7fffu + ((ub >> 16) & 1u)) >> 16;
  return ua | (ub << 16);
}
__device__ __forceinline__ float bf16_lo(unsigned v) { return __uint_as_float(v << 16); }
__device__ __forceinline__ float bf16_hi(unsigned v) { return __uint_as_float(v & 0xffff0000u); }

// ---- GEMM0: h0b[N,64 u32] = bf16(x @ W0), fused per-node alpha logits ----
__global__ __launch_bounds__(256) void gemm0_kernel(const float* __restrict__ x,
                                                    const float* __restrict__ W0,
                                                    const float* __restrict__ a_src0,
                                                    const float* __restrict__ a_dst0,
                                                    unsigned* __restrict__ h0b,
                                                    float* __restrict__ asrc0,
                                                    float* __restrict__ adst0) {
  __shared__ float xT[32][68];    // transposed x tile, padded
  __shared__ float Ws[32][128];
  int t = threadIdx.x;
  int rowbase = blockIdx.x * 64;
  int tx = t & 31, ty = t >> 5;   // tx: col-quad 0..31, ty: row-oct 0..7
  float acc[8][4];
#pragma unroll
  for (int i = 0; i < 8; i++)
#pragma unroll
    for (int j = 0; j < 4; j++) acc[i][j] = 0.f;

  for (int kt = 0; kt < 128; kt += 32) {
    {
      int row = t >> 3;   // 0..31
      int kq  = t & 7;    // k quad
#pragma unroll
      for (int rep = 0; rep < 2; rep++) {
        int r  = rowbase + row + rep * 32;
        int rc = r < NN ? r : NN - 1;
        float4 v = *(const float4*)&x[(size_t)rc * 128 + kt + kq * 4];
        xT[kq * 4 + 0][row + rep * 32] = v.x;
        xT[kq * 4 + 1][row + rep * 32] = v.y;
        xT[kq * 4 + 2][row + rep * 32] = v.z;
        xT[kq * 4 + 3][row + rep * 32] = v.w;
      }
    }
    {
      int c4  = t & 31;
      int kk0 = t >> 5;
#pragma unroll
      for (int rep = 0; rep < 4; rep++) {
        int kk = kk0 + rep * 8;
        float4 v = *(const float4*)&W0[(size_t)(kt + kk) * 128 + c4 * 4];
        *(float4*)&Ws[kk][c4 * 4] = v;
      }
    }
    __syncthreads();
#pragma unroll
    for (int k = 0; k < 32; k++) {
      float4 b  = *(const float4*)&Ws[k][tx * 4];
      float4 a0 = *(const float4*)&xT[k][ty * 8];
      float4 a1 = *(const float4*)&xT[k][ty * 8 + 4];
      float av[8] = {a0.x, a0.y, a0.z, a0.w, a1.x, a1.y, a1.z, a1.w};
      float bv[4] = {b.x, b.y, b.z, b.w};
#pragma unroll
      for (int i = 0; i < 8; i++)
#pragma unroll
        for (int j = 0; j < 4; j++) acc[i][j] += av[i] * bv[j];
    }
    __syncthreads();
  }
  // write h0 as packed bf16 (channels tx*4 .. tx*4+3 -> u32 pair at tx*2)
#pragma unroll
  for (int i = 0; i < 8; i++) {
    int r = rowbase + ty * 8 + i;
    if (r < NN) {
      uint2 pv;
      pv.x = pack_bf16(acc[i][0], acc[i][1]);
      pv.y = pack_bf16(acc[i][2], acc[i][3]);
      *(uint2*)&h0b[(size_t)r * 64 + tx * 2] = pv;
    }
  }
  // fused alpha logits: head = tx>>3; reduce over 8 consecutive lanes (one head = 32 cols)
  float4 asv = *(const float4*)&a_src0[tx * 4];
  float4 adv = *(const float4*)&a_dst0[tx * 4];
#pragma unroll
  for (int i = 0; i < 8; i++) {
    float ps = acc[i][0] * asv.x + acc[i][1] * asv.y + acc[i][2] * asv.z + acc[i][3] * asv.w;
    float pd = acc[i][0] * adv.x + acc[i][1] * adv.y + acc[i][2] * adv.z + acc[i][3] * adv.w;
#pragma unroll
    for (int mk = 1; mk < 8; mk <<= 1) { ps += __shfl_xor(ps, mk); pd += __shfl_xor(pd, mk); }
    int r = rowbase + ty * 8 + i;
    if ((tx & 7) == 0 && r < NN) {
      int head = tx >> 3;
      asrc0[r * 4 + head] = ps;
      adst0[r * 4 + head] = pd;
    }
  }
}

// ---------------- CSR build ----------------
__global__ void deg_kernel(const int* __restrict__ ei, int* __restrict__ deg) {
  int i = blockIdx.x * blockDim.x + threadIdx.x;
  if (i >= ETOT) return;
  int dst = (i < EE) ? ei[EE + i] : (i - EE);
  atomicAdd(&deg[dst], 1);
}

__global__ __launch_bounds__(256) void scanA_kernel(const int* __restrict__ deg,
                                                    int* __restrict__ scanned,
                                                    int* __restrict__ blocksums) {
  __shared__ int s[256];
  int t = threadIdx.x;
  int i = blockIdx.x * 256 + t;
  int v = (i < NN) ? deg[i] : 0;
  s[t] = v;
  __syncthreads();
  for (int off = 1; off < 256; off <<= 1) {
    int add = (t >= off) ? s[t - off] : 0;
    __syncthreads();
    s[t] += add;
    __syncthreads();
  }
  if (i < NN) scanned[i] = s[t];
  if (t == 255) blocksums[blockIdx.x] = s[255];
}

__global__ __launch_bounds__(512) void scanB_kernel(int* __restrict__ blocksums, int NB) {
  __shared__ int s[512];
  int t = threadIdx.x;
  int v = (t < NB) ? blocksums[t] : 0;
  s[t] = v;
  __syncthreads();
  for (int off = 1; off < 512; off <<= 1) {
    int add = (t >= off) ? s[t - off] : 0;
    __syncthreads();
    s[t] += add;
    __syncthreads();
  }
  if (t < NB) blocksums[t] = s[t] - v;  // exclusive block offset
}

__global__ __launch_bounds__(256) void scanC_kernel(const int* __restrict__ scanned,
                                                    const int* __restrict__ deg,
                                                    const int* __restrict__ blocksums,
                                                    int* __restrict__ rowptr) {
  int i = blockIdx.x * 256 + threadIdx.x;
  if (i < NN) rowptr[i] = blocksums[blockIdx.x] + scanned[i] - deg[i];
  if (i == 0) rowptr[NN] = ETOT;
}

__global__ void scatter_kernel(const int* __restrict__ ei, const int* __restrict__ rowptr,
                               int* __restrict__ cursor, int* __restrict__ csr_src) {
  int i = blockIdx.x * blockDim.x + threadIdx.x;
  if (i >= ETOT) return;
  int src, dst;
  if (i < EE) { src = ei[i]; dst = ei[EE + i]; }
  else        { src = dst = i - EE; }
  int pos = atomicAdd(&cursor[dst], 1);
  csr_src[rowptr[dst] + pos] = src;
}

// ---- layer-0 aggregate: one wave per node, single pass, bf16 gather ----
__global__ __launch_bounds__(256) void agg0_kernel(const int* __restrict__ csr_src,
                                                   const int* __restrict__ rowptr,
                                                   const float* __restrict__ asrc0,
                                                   const float* __restrict__ adst0,
                                                   const unsigned* __restrict__ h0b,
                                                   const float* __restrict__ b0,
                                                   float* __restrict__ agg0) {
  __shared__ float ws[4][4][72];   // [wave][head][edge] padded
  __shared__ int   ss[4][64];
  int t = threadIdx.x;
  int lane = t & 63, wv = t >> 6;
  int n = blockIdx.x * 4 + wv;
  if (n >= NN) return;
  int start = rowptr[n], end = rowptr[n + 1];
  float4 ad = *(const float4*)&adst0[(size_t)n * 4];
  int head = lane >> 4;            // channels 2*lane, 2*lane+1 -> head = lane/16
  float accx = 0.f, accy = 0.f;
  float d0 = 0.f, d1 = 0.f, d2 = 0.f, d3 = 0.f;

  for (int base = start; base < end; base += 64) {
    int cnt = min(64, end - base);
    if (lane < cnt) {
      int s = csr_src[base + lane];
      float4 as = *(const float4*)&asrc0[(size_t)s * 4];
      float w0 = __expf(lrelu(as.x + ad.x));
      float w1 = __expf(lrelu(as.y + ad.y));
      float w2 = __expf(lrelu(as.z + ad.z));
      float w3 = __expf(lrelu(as.w + ad.w));
      d0 += w0; d1 += w1; d2 += w2; d3 += w3;
      ss[wv][lane] = s;
      ws[wv][0][lane] = w0;
      ws[wv][1][lane] = w1;
      ws[wv][2][lane] = w2;
      ws[wv][3][lane] = w3;
    }
    __builtin_amdgcn_wave_barrier();
#pragma unroll 4
    for (int e = 0; e < cnt; e++) {
      int s = ss[wv][e];                 // broadcast
      float w = ws[wv][head][e];
      unsigned hv = h0b[(size_t)s * 64 + lane];
      accx += w * bf16_lo(hv);
      accy += w * bf16_hi(hv);
    }
    __builtin_amdgcn_wave_barrier();
  }
#pragma unroll
  for (int mk = 1; mk < 64; mk <<= 1) {
    d0 += __shfl_xor(d0, mk);
    d1 += __shfl_xor(d1, mk);
    d2 += __shfl_xor(d2, mk);
    d3 += __shfl_xor(d3, mk);
  }
  float dh = head == 0 ? d0 : head == 1 ? d1 : head == 2 ? d2 : d3;
  float rd = 1.f / dh;
  int c = lane * 2;
  float2 o;
  o.x = accx * rd + b0[c];
  o.y = accy * rd + b0[c + 1];
  *(float2*)&agg0[(size_t)n * 128 + c] = o;
}

// ---------------- BatchNorm stats / finalize ----------------
__global__ __launch_bounds__(256) void bnstats_kernel(const float* __restrict__ agg0,
                                                      float* __restrict__ bnsum,
                                                      float* __restrict__ bnsq) {
  int t = threadIdx.x;
  int c = t & 127;
  int g = blockIdx.x * 2 + (t >> 7);
  float s = 0.f, q = 0.f;
  for (int r = g; r < NN; r += 1024) {
    float v = agg0[(size_t)r * 128 + c];
    s += v;
    q += v * v;
  }
  __shared__ float ls[256], lq[256];
  ls[t] = s; lq[t] = q;
  __syncthreads();
  if (t < 128) {
    s = ls[t] + ls[t + 128];
    q = lq[t] + lq[t + 128];
    atomicAdd(&bnsum[c], s);
    atomicAdd(&bnsq[c], q);
  }
}

__global__ void bnfinal_kernel(const float* __restrict__ bnsum, const float* __restrict__ bnsq,
                               const float* __restrict__ gamma, const float* __restrict__ beta,
                               float* __restrict__ bnscale, float* __restrict__ bnshift) {
  int c = threadIdx.x;  // 128 threads
  float mu = bnsum[c] / (float)NN;
  float var = bnsq[c] / (float)NN - mu * mu;
  float sc = gamma[c] / sqrtf(var + BNEPS);
  bnscale[c] = sc;
  bnshift[c] = beta[c] - mu * sc;
}

// ---- GEMM1 (fused BN+ELU on input) + alpha1; h1 stored bf16 ----
__global__ __launch_bounds__(256) void gemm1_kernel(const float* __restrict__ agg0,
                                                    const float* __restrict__ bnscale,
                                                    const float* __restrict__ bnshift,
                                                    const float* __restrict__ W1,
                                                    const float* __restrict__ a_src1,
                                                    const float* __restrict__ a_dst1,
                                                    unsigned* __restrict__ h1b,
                                                    float* __restrict__ asrc1,
                                                    float* __restrict__ adst1) {
  __shared__ float W1s[128 * 40];
  __shared__ float rowbuf[4][130];
  int t = threadIdx.x;
  for (int i = t; i < 128 * 40; i += 256) W1s[i] = W1[i];
  __syncthreads();
  int lane = t & 63, wv = t >> 6;
  int r = blockIdx.x * 4 + wv;
  if (r >= NN) return;
  // stage BN+ELU transformed row (each lane: its 2 elements only)
  {
    float2 v = *(const float2*)&agg0[(size_t)r * 128 + lane * 2];
    float y0 = v.x * bnscale[lane * 2] + bnshift[lane * 2];
    float y1 = v.y * bnscale[lane * 2 + 1] + bnshift[lane * 2 + 1];
    y0 = y0 > 0.f ? y0 : expm1f(y0);
    y1 = y1 > 0.f ? y1 : expm1f(y1);
    rowbuf[wv][lane * 2] = y0;
    rowbuf[wv][lane * 2 + 1] = y1;
  }
  __builtin_amdgcn_wave_barrier();
  int c = lane;
  float acc = 0.f;
  if (c < 40) {
#pragma unroll 16
    for (int k = 0; k < 128; k++) acc += rowbuf[wv][k] * W1s[k * 40 + c];
  }
  float ps = (c < 40) ? acc * a_src1[c] : 0.f;
  float pd = (c < 40) ? acc * a_dst1[c] : 0.f;
#pragma unroll
  for (int m = 1; m < 64; m <<= 1) {
    ps += __shfl_xor(ps, m);
    pd += __shfl_xor(pd, m);
  }
  if (lane == 0) { asrc1[r] = ps; adst1[r] = pd; }
  // pack h1 row to bf16 (even lane packs {c, c+1})
  float accN = __shfl_xor(acc, 1);
  if (c < 40 && !(c & 1)) h1b[(size_t)r * 20 + (c >> 1)] = pack_bf16(acc, accN);
}

// ---- layer-1 aggregate: one wave per node, bf16 gather ----
__global__ __launch_bounds__(256) void agg1_kernel(const int* __restrict__ csr_src,
                                                   const int* __restrict__ rowptr,
                                                   const float* __restrict__ asrc1,
                                                   const float* __restrict__ adst1,
                                                   const unsigned* __restrict__ h1b,
                                                   const float* __restrict__ b1,
                                                   float* __restrict__ out) {
  __shared__ float ws[4][64];
  __shared__ int   ss[4][64];
  int t = threadIdx.x;
  int lane = t & 63, wv = t >> 6;
  int n = blockIdx.x * 4 + wv;
  if (n >= NN) return;
  int start = rowptr[n], end = rowptr[n + 1];
  float ad = adst1[n];
  float dsum = 0.f, acc0 = 0.f, acc1 = 0.f;
  for (int base = start; base < end; base += 64) {
    int cnt = min(64, end - base);
    if (lane < cnt) {
      int s = csr_src[base + lane];
      float w = __expf(lrelu(asrc1[s] + ad));
      dsum += w;
      ss[wv][lane] = s;
      ws[wv][lane] = w;
    }
    __builtin_amdgcn_wave_barrier();
    if (lane < 20) {
#pragma unroll 4
      for (int e = 0; e < cnt; e++) {
        int s = ss[wv][e];
        float w = ws[wv][e];
        unsigned hv = h1b[(size_t)s * 20 + lane];
        acc0 += w * bf16_lo(hv);
        acc1 += w * bf16_hi(hv);
      }
    }
    __builtin_amdgcn_wave_barrier();
  }
#pragma unroll
  for (int mk = 1; mk < 64; mk <<= 1) dsum += __shfl_xor(dsum, mk);
  float rd = 1.f / dsum;
  if (lane < 20) {
    float2 o;
    o.x = acc0 * rd + b1[lane * 2];
    o.y = acc1 * rd + b1[lane * 2 + 1];
    *(float2*)&out[(size_t)n * 40 + lane * 2] = o;
  }
}

// ---------------- host launch ----------------
extern "C" void kernel_launch(void* const* d_in, const int* in_sizes, int n_in,
                              void* d_out, int out_size, void* d_ws, size_t ws_size,
                              hipStream_t stream) {
  const float* x       = (const float*)d_in[0];
  const int*   ei      = (const int*)d_in[1];
  const float* W0      = (const float*)d_in[2];
  const float* a_src0  = (const float*)d_in[3];
  const float* a_dst0  = (const float*)d_in[4];
  const float* b0      = (const float*)d_in[5];
  const float* gamma0  = (const float*)d_in[6];
  const float* beta0   = (const float*)d_in[7];
  const float* W1      = (const float*)d_in[8];
  const float* a_src1  = (const float*)d_in[9];
  const float* a_dst1  = (const float*)d_in[10];
  const float* b1      = (const float*)d_in[11];
  float* out = (float*)d_out;

  char* ws = (char*)d_ws;
  size_t off = 0;
  auto alloc = [&](size_t bytes) {
    void* p = ws + off;
    off += (bytes + 255) & ~(size_t)255;
    return p;
  };
  unsigned* h0b   = (unsigned*)alloc((size_t)NN * 64 * 4);   // bf16x2
  float* agg0     = (float*)alloc((size_t)NN * 128 * 4);
  unsigned* h1b   = (unsigned*)alloc((size_t)NN * 20 * 4);   // bf16x2
  float* asrc0    = (float*)alloc((size_t)NN * 4 * 4);
  float* adst0    = (float*)alloc((size_t)NN * 4 * 4);
  float* asrc1    = (float*)alloc((size_t)NN * 4);
  float* adst1    = (float*)alloc((size_t)NN * 4);
  int*   deg      = (int*)alloc((size_t)NN * 4);       // zeroed below (contiguous region)
  int*   cursor   = (int*)alloc((size_t)NN * 4);
  float* bnsum    = (float*)alloc(128 * 4);
  float* bnsq     = (float*)alloc(128 * 4);
  float* bnscale  = (float*)alloc(128 * 4);
  float* bnshift  = (float*)alloc(128 * 4);
  int*   rowptr   = (int*)alloc((size_t)(NN + 1) * 4);
  int*   scanned  = (int*)alloc((size_t)NN * 4);
  int*   csr      = (int*)alloc((size_t)ETOT * 4);
  int*   bsums    = (int*)alloc(512 * 4);
  (void)ws_size; (void)in_sizes; (void)n_in; (void)out_size;

  size_t zbytes = (char*)(bnsq + 128) - (char*)deg;
  hipMemsetAsync(deg, 0, zbytes, stream);

  const int NB = (NN + 255) / 256;
  const int egrid = (ETOT + 255) / 256;

  gemm0_kernel<<<(NN + 63) / 64, 256, 0, stream>>>(x, W0, a_src0, a_dst0, h0b, asrc0, adst0);
  deg_kernel<<<egrid, 256, 0, stream>>>(ei, deg);
  scanA_kernel<<<NB, 256, 0, stream>>>(deg, scanned, bsums);
  scanB_kernel<<<1, 512, 0, stream>>>(bsums, NB);
  scanC_kernel<<<NB, 256, 0, stream>>>(scanned, deg, bsums, rowptr);
  scatter_kernel<<<egrid, 256, 0, stream>>>(ei, rowptr, cursor, csr);
  agg0_kernel<<<(NN + 3) / 4, 256, 0, stream>>>(csr, rowptr, asrc0, adst0, h0b, b0, agg0);
  bnstats_kernel<<<512, 256, 0, stream>>>(agg0, bnsum, bnsq);
  bnfinal_kernel<<<1, 128, 0, stream>>>(bnsum, bnsq, gamma0, beta0, bnscale, bnshift);
  gemm1_kernel<<<(NN + 3) / 4, 256, 0, stream>>>(agg0, bnscale, bnshift, W1, a_src1, a_dst1,
                                                 h1b, asrc1, adst1);
  agg1_kernel<<<(NN + 3) / 4, 256, 0, stream>>>(csr, rowptr, asrc1, adst1, h1b, b1, out);
}

// Round 4
// 367.739 us; speedup vs baseline: 2.2568x; 1.4286x over previous
//
#include <hip/hip_runtime.h>
#include <hip/hip_bf16.h>
#include <math.h>

#define NN   100000
#define EE   1600000
#define ETOT (NN + EE)
#define IND  128
#define HD   128    // HEADS*HID
#define OD   40
#define NEG  0.2f
#define BNEPS 1e-5f

typedef __attribute__((ext_vector_type(8))) short bf16x8;
typedef __attribute__((ext_vector_type(4))) float f32x4;

__device__ __forceinline__ float lrelu(float x) { return x > 0.f ? x : NEG * x; }

// pack two floats to bf16x2 (RNE)
__device__ __forceinline__ unsigned pack_bf16(float a, float b) {
  unsigned ua = __float_as_uint(a), ub = __float_as_uint(b);
  ua = (ua + 0x7fffu + ((ua >> 16) & 1u)) >> 16;
  ub = (ub + 0x7fffu + ((ub >> 16) & 1u)) >> 16;
  return ua | (ub << 16);
}
__device__ __forceinline__ float bf16_lo(unsigned v) { return __uint_as_float(v << 16); }
__device__ __forceinline__ float bf16_hi(unsigned v) { return __uint_as_float(v & 0xffff0000u); }

// ---- GEMM0: h0b[N,64 u32] = bf16(x @ W0), fused per-node alpha logits ----
__global__ __launch_bounds__(256) void gemm0_kernel(const float* __restrict__ x,
                                                    const float* __restrict__ W0,
                                                    const float* __restrict__ a_src0,
                                                    const float* __restrict__ a_dst0,
                                                    unsigned* __restrict__ h0b,
                                                    float* __restrict__ asrc0,
                                                    float* __restrict__ adst0) {
  __shared__ float xT[32][68];    // transposed x tile, padded
  __shared__ float Ws[32][128];
  int t = threadIdx.x;
  int rowbase = blockIdx.x * 64;
  int tx = t & 31, ty = t >> 5;   // tx: col-quad 0..31, ty: row-oct 0..7
  float acc[8][4];
#pragma unroll
  for (int i = 0; i < 8; i++)
#pragma unroll
    for (int j = 0; j < 4; j++) acc[i][j] = 0.f;

  for (int kt = 0; kt < 128; kt += 32) {
    {
      int row = t >> 3;   // 0..31
      int kq  = t & 7;    // k quad
#pragma unroll
      for (int rep = 0; rep < 2; rep++) {
        int r  = rowbase + row + rep * 32;
        int rc = r < NN ? r : NN - 1;
        float4 v = *(const float4*)&x[(size_t)rc * 128 + kt + kq * 4];
        xT[kq * 4 + 0][row + rep * 32] = v.x;
        xT[kq * 4 + 1][row + rep * 32] = v.y;
        xT[kq * 4 + 2][row + rep * 32] = v.z;
        xT[kq * 4 + 3][row + rep * 32] = v.w;
      }
    }
    {
      int c4  = t & 31;
      int kk0 = t >> 5;
#pragma unroll
      for (int rep = 0; rep < 4; rep++) {
        int kk = kk0 + rep * 8;
        float4 v = *(const float4*)&W0[(size_t)(kt + kk) * 128 + c4 * 4];
        *(float4*)&Ws[kk][c4 * 4] = v;
      }
    }
    __syncthreads();
#pragma unroll
    for (int k = 0; k < 32; k++) {
      float4 b  = *(const float4*)&Ws[k][tx * 4];
      float4 a0 = *(const float4*)&xT[k][ty * 8];
      float4 a1 = *(const float4*)&xT[k][ty * 8 + 4];
      float av[8] = {a0.x, a0.y, a0.z, a0.w, a1.x, a1.y, a1.z, a1.w};
      float bv[4] = {b.x, b.y, b.z, b.w};
#pragma unroll
      for (int i = 0; i < 8; i++)
#pragma unroll
        for (int j = 0; j < 4; j++) acc[i][j] += av[i] * bv[j];
    }
    __syncthreads();
  }
  // write h0 as packed bf16 (channels tx*4 .. tx*4+3 -> u32 pair at tx*2)
#pragma unroll
  for (int i = 0; i < 8; i++) {
    int r = rowbase + ty * 8 + i;
    if (r < NN) {
      uint2 pv;
      pv.x = pack_bf16(acc[i][0], acc[i][1]);
      pv.y = pack_bf16(acc[i][2], acc[i][3]);
      *(uint2*)&h0b[(size_t)r * 64 + tx * 2] = pv;
    }
  }
  // fused alpha logits: head = tx>>3; reduce over 8 consecutive lanes (one head = 32 cols)
  float4 asv = *(const float4*)&a_src0[tx * 4];
  float4 adv = *(const float4*)&a_dst0[tx * 4];
#pragma unroll
  for (int i = 0; i < 8; i++) {
    float ps = acc[i][0] * asv.x + acc[i][1] * asv.y + acc[i][2] * asv.z + acc[i][3] * asv.w;
    float pd = acc[i][0] * adv.x + acc[i][1] * adv.y + acc[i][2] * adv.z + acc[i][3] * adv.w;
#pragma unroll
    for (int mk = 1; mk < 8; mk <<= 1) { ps += __shfl_xor(ps, mk); pd += __shfl_xor(pd, mk); }
    int r = rowbase + ty * 8 + i;
    if ((tx & 7) == 0 && r < NN) {
      int head = tx >> 3;
      asrc0[r * 4 + head] = ps;
      adst0[r * 4 + head] = pd;
    }
  }
}

// ---------------- CSR build ----------------
// deg + per-edge rank in one pass (rank = slot within segment)
__global__ void degrank_kernel(const int* __restrict__ ei, int* __restrict__ deg,
                               int* __restrict__ rank) {
  int i = blockIdx.x * blockDim.x + threadIdx.x;
  if (i >= ETOT) return;
  int dst = (i < EE) ? ei[EE + i] : (i - EE);
  rank[i] = atomicAdd(&deg[dst], 1);
}

__global__ __launch_bounds__(256) void scanA_kernel(const int* __restrict__ deg,
                                                    int* __restrict__ scanned,
                                                    int* __restrict__ blocksums) {
  __shared__ int s[256];
  int t = threadIdx.x;
  int i = blockIdx.x * 256 + t;
  int v = (i < NN) ? deg[i] : 0;
  s[t] = v;
  __syncthreads();
  for (int off = 1; off < 256; off <<= 1) {
    int add = (t >= off) ? s[t - off] : 0;
    __syncthreads();
    s[t] += add;
    __syncthreads();
  }
  if (i < NN) scanned[i] = s[t];
  if (t == 255) blocksums[blockIdx.x] = s[255];
}

__global__ __launch_bounds__(512) void scanB_kernel(int* __restrict__ blocksums, int NB) {
  __shared__ int s[512];
  int t = threadIdx.x;
  int v = (t < NB) ? blocksums[t] : 0;
  s[t] = v;
  __syncthreads();
  for (int off = 1; off < 512; off <<= 1) {
    int add = (t >= off) ? s[t - off] : 0;
    __syncthreads();
    s[t] += add;
    __syncthreads();
  }
  if (t < NB) blocksums[t] = s[t] - v;  // exclusive block offset
}

__global__ __launch_bounds__(256) void scanC_kernel(const int* __restrict__ scanned,
                                                    const int* __restrict__ deg,
                                                    const int* __restrict__ blocksums,
                                                    int* __restrict__ rowptr) {
  int i = blockIdx.x * 256 + threadIdx.x;
  if (i < NN) rowptr[i] = blocksums[blockIdx.x] + scanned[i] - deg[i];
  if (i == 0) rowptr[NN] = ETOT;
}

// atomic-free scatter using precomputed rank
__global__ void scatter_kernel(const int* __restrict__ ei, const int* __restrict__ rowptr,
                               const int* __restrict__ rank, int* __restrict__ csr_src) {
  int i = blockIdx.x * blockDim.x + threadIdx.x;
  if (i >= ETOT) return;
  int src, dst;
  if (i < EE) { src = ei[i]; dst = ei[EE + i]; }
  else        { src = dst = i - EE; }
  csr_src[rowptr[dst] + rank[i]] = src;
}

// ---- layer-0 aggregate: one wave per node, single pass, bf16 gather ----
__global__ __launch_bounds__(256) void agg0_kernel(const int* __restrict__ csr_src,
                                                   const int* __restrict__ rowptr,
                                                   const float* __restrict__ asrc0,
                                                   const float* __restrict__ adst0,
                                                   const unsigned* __restrict__ h0b,
                                                   const float* __restrict__ b0,
                                                   float* __restrict__ agg0) {
  __shared__ float ws[4][4][72];   // [wave][head][edge] padded
  __shared__ int   ss[4][64];
  int t = threadIdx.x;
  int lane = t & 63, wv = t >> 6;
  int n = blockIdx.x * 4 + wv;
  if (n >= NN) return;
  int start = rowptr[n], end = rowptr[n + 1];
  float4 ad = *(const float4*)&adst0[(size_t)n * 4];
  int head = lane >> 4;            // channels 2*lane, 2*lane+1 -> head = lane/16
  float accx = 0.f, accy = 0.f;
  float d0 = 0.f, d1 = 0.f, d2 = 0.f, d3 = 0.f;

  for (int base = start; base < end; base += 64) {
    int cnt = min(64, end - base);
    if (lane < cnt) {
      int s = csr_src[base + lane];
      float4 as = *(const float4*)&asrc0[(size_t)s * 4];
      float w0 = __expf(lrelu(as.x + ad.x));
      float w1 = __expf(lrelu(as.y + ad.y));
      float w2 = __expf(lrelu(as.z + ad.z));
      float w3 = __expf(lrelu(as.w + ad.w));
      d0 += w0; d1 += w1; d2 += w2; d3 += w3;
      ss[wv][lane] = s;
      ws[wv][0][lane] = w0;
      ws[wv][1][lane] = w1;
      ws[wv][2][lane] = w2;
      ws[wv][3][lane] = w3;
    }
    __builtin_amdgcn_wave_barrier();
#pragma unroll 4
    for (int e = 0; e < cnt; e++) {
      int s = ss[wv][e];                 // broadcast
      float w = ws[wv][head][e];
      unsigned hv = h0b[(size_t)s * 64 + lane];
      accx += w * bf16_lo(hv);
      accy += w * bf16_hi(hv);
    }
    __builtin_amdgcn_wave_barrier();
  }
#pragma unroll
  for (int mk = 1; mk < 64; mk <<= 1) {
    d0 += __shfl_xor(d0, mk);
    d1 += __shfl_xor(d1, mk);
    d2 += __shfl_xor(d2, mk);
    d3 += __shfl_xor(d3, mk);
  }
  float dh = head == 0 ? d0 : head == 1 ? d1 : head == 2 ? d2 : d3;
  float rd = 1.f / dh;
  int c = lane * 2;
  float2 o;
  o.x = accx * rd + b0[c];
  o.y = accy * rd + b0[c + 1];
  *(float2*)&agg0[(size_t)n * 128 + c] = o;
}

// ---------------- BatchNorm stats / finalize ----------------
__global__ __launch_bounds__(256) void bnstats_kernel(const float* __restrict__ agg0,
                                                      float* __restrict__ bnsum,
                                                      float* __restrict__ bnsq) {
  int t = threadIdx.x;
  int c = t & 127;
  int g = blockIdx.x * 2 + (t >> 7);
  float s = 0.f, q = 0.f;
  for (int r = g; r < NN; r += 1024) {
    float v = agg0[(size_t)r * 128 + c];
    s += v;
    q += v * v;
  }
  __shared__ float ls[256], lq[256];
  ls[t] = s; lq[t] = q;
  __syncthreads();
  if (t < 128) {
    s = ls[t] + ls[t + 128];
    q = lq[t] + lq[t + 128];
    atomicAdd(&bnsum[c], s);
    atomicAdd(&bnsq[c], q);
  }
}

__global__ void bnfinal_kernel(const float* __restrict__ bnsum, const float* __restrict__ bnsq,
                               const float* __restrict__ gamma, const float* __restrict__ beta,
                               float* __restrict__ bnscale, float* __restrict__ bnshift) {
  int c = threadIdx.x;  // 128 threads
  float mu = bnsum[c] / (float)NN;
  float var = bnsq[c] / (float)NN - mu * mu;
  float sc = gamma[c] / sqrtf(var + BNEPS);
  bnscale[c] = sc;
  bnshift[c] = beta[c] - mu * sc;
}

// ---- GEMM1 via MFMA: fused BN+ELU input transform, alpha1 epilogue, bf16 h1 ----
// 64 rows/block, 4 waves; wave w owns rows w*16..w*16+15, 3 col-tiles of 16 (40->48 pad).
// A and B frags use the SAME contiguous (group,elem)->k mapping, so the MFMA contraction
// is correct independent of the hardware's internal k layout.
__global__ __launch_bounds__(256) void gemm1_kernel(const float* __restrict__ agg0,
                                                    const float* __restrict__ bnscale,
                                                    const float* __restrict__ bnshift,
                                                    const float* __restrict__ W1,
                                                    const float* __restrict__ a_src1,
                                                    const float* __restrict__ a_dst1,
                                                    unsigned* __restrict__ h1b,
                                                    float* __restrict__ asrc1,
                                                    float* __restrict__ adst1) {
  __shared__ __align__(16) unsigned As[64][68];  // bf16x2, row stride 68 u32 (2-way banks)
  __shared__ __align__(16) unsigned Wt[48][68];  // W1^T bf16x2: [col][k/2]
  int t = threadIdx.x;
  int rowbase = blockIdx.x * 64;

  // stage W1^T (48 cols padded with zeros, 64 u32 of k each)
  for (int idx = t; idx < 48 * 64; idx += 256) {
    int c = idx >> 6, kp = idx & 63;
    float lo = (c < OD) ? W1[(size_t)(2 * kp) * OD + c] : 0.f;
    float hi = (c < OD) ? W1[(size_t)(2 * kp + 1) * OD + c] : 0.f;
    Wt[c][kp] = pack_bf16(lo, hi);
  }
  // stage A rows with BN+ELU, packed bf16
  for (int idx = t; idx < 64 * 32; idx += 256) {
    int row = idx >> 5, k4 = idx & 31;
    int r = rowbase + row;
    int rc = r < NN ? r : NN - 1;
    int k = k4 * 4;
    float4 v  = *(const float4*)&agg0[(size_t)rc * 128 + k];
    float4 sc = *(const float4*)&bnscale[k];
    float4 sh = *(const float4*)&bnshift[k];
    float y0 = v.x * sc.x + sh.x;
    float y1 = v.y * sc.y + sh.y;
    float y2 = v.z * sc.z + sh.z;
    float y3 = v.w * sc.w + sh.w;
    y0 = y0 > 0.f ? y0 : expm1f(y0);
    y1 = y1 > 0.f ? y1 : expm1f(y1);
    y2 = y2 > 0.f ? y2 : expm1f(y2);
    y3 = y3 > 0.f ? y3 : expm1f(y3);
    As[row][k4 * 2]     = pack_bf16(y0, y1);
    As[row][k4 * 2 + 1] = pack_bf16(y2, y3);
  }
  __syncthreads();

  int lane = t & 63, w = t >> 6;
  int mrow = lane & 15, g = lane >> 4;
  f32x4 acc0 = {0.f, 0.f, 0.f, 0.f};
  f32x4 acc1 = {0.f, 0.f, 0.f, 0.f};
  f32x4 acc2 = {0.f, 0.f, 0.f, 0.f};
#pragma unroll
  for (int ks = 0; ks < 4; ks++) {
    // contiguous frag: k = ks*32 + g*8 + 0..7  -> u32 offset ks*16 + g*4
    bf16x8 a = *(const bf16x8*)&As[w * 16 + mrow][ks * 16 + g * 4];
    bf16x8 b0v = *(const bf16x8*)&Wt[mrow][ks * 16 + g * 4];
    bf16x8 b1v = *(const bf16x8*)&Wt[16 + mrow][ks * 16 + g * 4];
    bf16x8 b2v = *(const bf16x8*)&Wt[32 + mrow][ks * 16 + g * 4];
    acc0 = __builtin_amdgcn_mfma_f32_16x16x32_bf16(a, b0v, acc0, 0, 0, 0);
    acc1 = __builtin_amdgcn_mfma_f32_16x16x32_bf16(a, b1v, acc1, 0, 0, 0);
    acc2 = __builtin_amdgcn_mfma_f32_16x16x32_bf16(a, b2v, acc2, 0, 0, 0);
  }
  // epilogue: C layout col = lane&15 (+16*ct), row = g*4 + reg
  int col = lane & 15;
  float as0 = (col < OD)      ? a_src1[col]      : 0.f;
  float as1 = (16 + col < OD) ? a_src1[16 + col] : 0.f;
  float as2 = (32 + col < OD) ? a_src1[32 + col] : 0.f;
  float ad0 = (col < OD)      ? a_dst1[col]      : 0.f;
  float ad1 = (16 + col < OD) ? a_dst1[16 + col] : 0.f;
  float ad2 = (32 + col < OD) ? a_dst1[32 + col] : 0.f;
#pragma unroll
  for (int reg = 0; reg < 4; reg++) {
    int r = rowbase + w * 16 + g * 4 + reg;
    float v0 = acc0[reg], v1 = acc1[reg], v2 = acc2[reg];
    float ps = v0 * as0 + v1 * as1 + v2 * as2;
    float pd = v0 * ad0 + v1 * ad1 + v2 * ad2;
#pragma unroll
    for (int mk = 1; mk < 16; mk <<= 1) { ps += __shfl_xor(ps, mk); pd += __shfl_xor(pd, mk); }
    bool rok = r < NN;
    if ((lane & 15) == 0 && rok) { asrc1[r] = ps; adst1[r] = pd; }
    // pack h1 bf16: even col packs (c, c+1)
    float n0 = __shfl_xor(v0, 1), n1 = __shfl_xor(v1, 1), n2 = __shfl_xor(v2, 1);
    if (!(col & 1) && rok) {
      h1b[(size_t)r * 20 + ((col) >> 1)]      = pack_bf16(v0, n0);
      h1b[(size_t)r * 20 + ((16 + col) >> 1)] = pack_bf16(v1, n1);
      if (32 + col < OD) h1b[(size_t)r * 20 + ((32 + col) >> 1)] = pack_bf16(v2, n2);
    }
  }
}

// ---- layer-1 aggregate: one wave per node, bf16 gather ----
__global__ __launch_bounds__(256) void agg1_kernel(const int* __restrict__ csr_src,
                                                   const int* __restrict__ rowptr,
                                                   const float* __restrict__ asrc1,
                                                   const float* __restrict__ adst1,
                                                   const unsigned* __restrict__ h1b,
                                                   const float* __restrict__ b1,
                                                   float* __restrict__ out) {
  __shared__ float ws[4][64];
  __shared__ int   ss[4][64];
  int t = threadIdx.x;
  int lane = t & 63, wv = t >> 6;
  int n = blockIdx.x * 4 + wv;
  if (n >= NN) return;
  int start = rowptr[n], end = rowptr[n + 1];
  float ad = adst1[n];
  float dsum = 0.f, acc0 = 0.f, acc1 = 0.f;
  for (int base = start; base < end; base += 64) {
    int cnt = min(64, end - base);
    if (lane < cnt) {
      int s = csr_src[base + lane];
      float w = __expf(lrelu(asrc1[s] + ad));
      dsum += w;
      ss[wv][lane] = s;
      ws[wv][lane] = w;
    }
    __builtin_amdgcn_wave_barrier();
    if (lane < 20) {
#pragma unroll 4
      for (int e = 0; e < cnt; e++) {
        int s = ss[wv][e];
        float w = ws[wv][e];
        unsigned hv = h1b[(size_t)s * 20 + lane];
        acc0 += w * bf16_lo(hv);
        acc1 += w * bf16_hi(hv);
      }
    }
    __builtin_amdgcn_wave_barrier();
  }
#pragma unroll
  for (int mk = 1; mk < 64; mk <<= 1) dsum += __shfl_xor(dsum, mk);
  float rd = 1.f / dsum;
  if (lane < 20) {
    float2 o;
    o.x = acc0 * rd + b1[lane * 2];
    o.y = acc1 * rd + b1[lane * 2 + 1];
    *(float2*)&out[(size_t)n * 40 + lane * 2] = o;
  }
}

// ---------------- host launch ----------------
extern "C" void kernel_launch(void* const* d_in, const int* in_sizes, int n_in,
                              void* d_out, int out_size, void* d_ws, size_t ws_size,
                              hipStream_t stream) {
  const float* x       = (const float*)d_in[0];
  const int*   ei      = (const int*)d_in[1];
  const float* W0      = (const float*)d_in[2];
  const float* a_src0  = (const float*)d_in[3];
  const float* a_dst0  = (const float*)d_in[4];
  const float* b0      = (const float*)d_in[5];
  const float* gamma0  = (const float*)d_in[6];
  const float* beta0   = (const float*)d_in[7];
  const float* W1      = (const float*)d_in[8];
  const float* a_src1  = (const float*)d_in[9];
  const float* a_dst1  = (const float*)d_in[10];
  const float* b1      = (const float*)d_in[11];
  float* out = (float*)d_out;

  char* ws = (char*)d_ws;
  size_t off = 0;
  auto alloc = [&](size_t bytes) {
    void* p = ws + off;
    off += (bytes + 255) & ~(size_t)255;
    return p;
  };
  // zero-region first: deg, bnsum, bnsq (contiguous)
  int*   deg      = (int*)alloc((size_t)NN * 4);
  float* bnsum    = (float*)alloc(128 * 4);
  float* bnsq     = (float*)alloc(128 * 4);
  unsigned* h0b   = (unsigned*)alloc((size_t)NN * 64 * 4);   // bf16x2
  float* agg0     = (float*)alloc((size_t)NN * 128 * 4);
  unsigned* h1b   = (unsigned*)alloc((size_t)NN * 20 * 4);   // bf16x2
  float* asrc0    = (float*)alloc((size_t)NN * 4 * 4);
  float* adst0    = (float*)alloc((size_t)NN * 4 * 4);
  float* asrc1    = (float*)alloc((size_t)NN * 4);
  float* adst1    = (float*)alloc((size_t)NN * 4);
  float* bnscale  = (float*)alloc(128 * 4);
  float* bnshift  = (float*)alloc(128 * 4);
  int*   rowptr   = (int*)alloc((size_t)(NN + 1) * 4);
  int*   scanned  = (int*)alloc((size_t)NN * 4);
  int*   csr      = (int*)alloc((size_t)ETOT * 4);
  int*   rank     = (int*)alloc((size_t)ETOT * 4);
  int*   bsums    = (int*)alloc(512 * 4);
  (void)ws_size; (void)in_sizes; (void)n_in; (void)out_size;

  size_t zbytes = (char*)(bnsq + 128) - (char*)deg;
  hipMemsetAsync(deg, 0, zbytes, stream);

  const int NB = (NN + 255) / 256;
  const int egrid = (ETOT + 255) / 256;

  gemm0_kernel<<<(NN + 63) / 64, 256, 0, stream>>>(x, W0, a_src0, a_dst0, h0b, asrc0, adst0);
  degrank_kernel<<<egrid, 256, 0, stream>>>(ei, deg, rank);
  scanA_kernel<<<NB, 256, 0, stream>>>(deg, scanned, bsums);
  scanB_kernel<<<1, 512, 0, stream>>>(bsums, NB);
  scanC_kernel<<<NB, 256, 0, stream>>>(scanned, deg, bsums, rowptr);
  scatter_kernel<<<egrid, 256, 0, stream>>>(ei, rowptr, rank, csr);
  agg0_kernel<<<(NN + 3) / 4, 256, 0, stream>>>(csr, rowptr, asrc0, adst0, h0b, b0, agg0);
  bnstats_kernel<<<512, 256, 0, stream>>>(agg0, bnsum, bnsq);
  bnfinal_kernel<<<1, 128, 0, stream>>>(bnsum, bnsq, gamma0, beta0, bnscale, bnshift);
  gemm1_kernel<<<(NN + 63) / 64, 256, 0, stream>>>(agg0, bnscale, bnshift, W1, a_src1, a_dst1,
                                                   h1b, asrc1, adst1);
  agg1_kernel<<<(NN + 3) / 4, 256, 0, stream>>>(csr, rowptr, asrc1, adst1, h1b, b1, out);
}

// Round 5
// 346.911 us; speedup vs baseline: 2.3923x; 1.0600x over previous
//
#include <hip/hip_runtime.h>
#include <hip/hip_bf16.h>
#include <math.h>

#define NN   100000
#define EE   1600000
#define ETOT (NN + EE)
#define IND  128
#define HD   128    // HEADS*HID
#define OD   40
#define NEG  0.2f
#define BNEPS 1e-5f

typedef __attribute__((ext_vector_type(8))) short bf16x8;
typedef __attribute__((ext_vector_type(4))) float f32x4;

__device__ __forceinline__ float lrelu(float x) { return x > 0.f ? x : NEG * x; }

// pack two floats to bf16x2 (RNE)
__device__ __forceinline__ unsigned pack_bf16(float a, float b) {
  unsigned ua = __float_as_uint(a), ub = __float_as_uint(b);
  ua = (ua + 0x7fffu + ((ua >> 16) & 1u)) >> 16;
  ub = (ub + 0x7fffu + ((ub >> 16) & 1u)) >> 16;
  return ua | (ub << 16);
}
__device__ __forceinline__ float bf16_lo(unsigned v) { return __uint_as_float(v << 16); }
__device__ __forceinline__ float bf16_hi(unsigned v) { return __uint_as_float(v & 0xffff0000u); }

// ---- one-shot: pack W0 transposed to bf16x2  w0t[n][kp] = (W0[2kp][n], W0[2kp+1][n]) ----
__global__ __launch_bounds__(256) void w0pack_kernel(const float* __restrict__ W0,
                                                     unsigned* __restrict__ w0t) {
  int idx = blockIdx.x * 256 + threadIdx.x;
  if (idx >= 128 * 64) return;
  int n = idx & 127, kp = idx >> 7;   // coalesced reads along n
  float lo = W0[(size_t)(2 * kp) * 128 + n];
  float hi = W0[(size_t)(2 * kp + 1) * 128 + n];
  w0t[n * 64 + kp] = pack_bf16(lo, hi);
}

// ---- GEMM0 via MFMA: h0b = bf16(x @ W0), fused per-node/per-head alpha logits ----
// 64 rows x 128 cols per block, 4 waves; wave w: rows w*16..+15, 8 n-tiles of 16.
__global__ __launch_bounds__(256) void gemm0_kernel(const float* __restrict__ x,
                                                    const unsigned* __restrict__ w0t,
                                                    const float* __restrict__ a_src0,
                                                    const float* __restrict__ a_dst0,
                                                    unsigned* __restrict__ h0b,
                                                    float* __restrict__ asrc0,
                                                    float* __restrict__ adst0) {
  __shared__ __align__(16) unsigned As[64][68];   // bf16x2 [row][k/2]
  __shared__ __align__(16) unsigned Wt[128][68];  // bf16x2 [col][k/2]
  int t = threadIdx.x;
  int rowbase = blockIdx.x * 64;
  for (int idx = t; idx < 128 * 64; idx += 256) {
    Wt[idx >> 6][idx & 63] = w0t[idx];
  }
  for (int idx = t; idx < 64 * 64; idx += 256) {
    int row = idx >> 6, kp = idx & 63;
    int r = rowbase + row;
    int rc = r < NN ? r : NN - 1;
    float2 v = *(const float2*)&x[(size_t)rc * 128 + kp * 2];
    As[row][kp] = pack_bf16(v.x, v.y);
  }
  __syncthreads();

  int lane = t & 63, w = t >> 6;
  int mrow = lane & 15, g = lane >> 4;
  f32x4 acc[8];
#pragma unroll
  for (int nt = 0; nt < 8; nt++) acc[nt] = (f32x4){0.f, 0.f, 0.f, 0.f};
#pragma unroll
  for (int ks = 0; ks < 4; ks++) {
    bf16x8 a = *(const bf16x8*)&As[w * 16 + mrow][ks * 16 + g * 4];
#pragma unroll
    for (int nt = 0; nt < 8; nt++) {
      bf16x8 b = *(const bf16x8*)&Wt[nt * 16 + mrow][ks * 16 + g * 4];
      acc[nt] = __builtin_amdgcn_mfma_f32_16x16x32_bf16(a, b, acc[nt], 0, 0, 0);
    }
  }
  // epilogue: C layout col = nt*16 + (lane&15), row = g*4 + reg  (verified pattern)
  int col = lane & 15;
  float as_[8], ad_[8];
#pragma unroll
  for (int nt = 0; nt < 8; nt++) {
    as_[nt] = a_src0[nt * 16 + col];
    ad_[nt] = a_dst0[nt * 16 + col];
  }
#pragma unroll
  for (int reg = 0; reg < 4; reg++) {
    int r = rowbase + w * 16 + g * 4 + reg;
    bool rok = r < NN;
    float hs0 = acc[0][reg] * as_[0] + acc[1][reg] * as_[1];
    float hs1 = acc[2][reg] * as_[2] + acc[3][reg] * as_[3];
    float hs2 = acc[4][reg] * as_[4] + acc[5][reg] * as_[5];
    float hs3 = acc[6][reg] * as_[6] + acc[7][reg] * as_[7];
    float hd0 = acc[0][reg] * ad_[0] + acc[1][reg] * ad_[1];
    float hd1 = acc[2][reg] * ad_[2] + acc[3][reg] * ad_[3];
    float hd2 = acc[4][reg] * ad_[4] + acc[5][reg] * ad_[5];
    float hd3 = acc[6][reg] * ad_[6] + acc[7][reg] * ad_[7];
#pragma unroll
    for (int mk = 1; mk < 16; mk <<= 1) {
      hs0 += __shfl_xor(hs0, mk); hs1 += __shfl_xor(hs1, mk);
      hs2 += __shfl_xor(hs2, mk); hs3 += __shfl_xor(hs3, mk);
      hd0 += __shfl_xor(hd0, mk); hd1 += __shfl_xor(hd1, mk);
      hd2 += __shfl_xor(hd2, mk); hd3 += __shfl_xor(hd3, mk);
    }
    if ((lane & 15) == 0 && rok) {
      asrc0[r * 4 + 0] = hs0; asrc0[r * 4 + 1] = hs1;
      asrc0[r * 4 + 2] = hs2; asrc0[r * 4 + 3] = hs3;
      adst0[r * 4 + 0] = hd0; adst0[r * 4 + 1] = hd1;
      adst0[r * 4 + 2] = hd2; adst0[r * 4 + 3] = hd3;
    }
#pragma unroll
    for (int nt = 0; nt < 8; nt++) {
      float v = acc[nt][reg];
      float nv = __shfl_xor(v, 1);
      if (!(col & 1) && rok) h0b[(size_t)r * 64 + nt * 8 + (col >> 1)] = pack_bf16(v, nv);
    }
  }
}

// ---------------- CSR build ----------------
__global__ void degrank_kernel(const int* __restrict__ ei, int* __restrict__ deg,
                               int* __restrict__ rank) {
  int i = blockIdx.x * blockDim.x + threadIdx.x;
  if (i >= ETOT) return;
  int dst = (i < EE) ? ei[EE + i] : (i - EE);
  rank[i] = atomicAdd(&deg[dst], 1);
}

__global__ __launch_bounds__(256) void scanA_kernel(const int* __restrict__ deg,
                                                    int* __restrict__ scanned,
                                                    int* __restrict__ blocksums) {
  __shared__ int s[256];
  int t = threadIdx.x;
  int i = blockIdx.x * 256 + t;
  int v = (i < NN) ? deg[i] : 0;
  s[t] = v;
  __syncthreads();
  for (int off = 1; off < 256; off <<= 1) {
    int add = (t >= off) ? s[t - off] : 0;
    __syncthreads();
    s[t] += add;
    __syncthreads();
  }
  if (i < NN) scanned[i] = s[t];
  if (t == 255) blocksums[blockIdx.x] = s[255];
}

__global__ __launch_bounds__(512) void scanB_kernel(int* __restrict__ blocksums, int NB) {
  __shared__ int s[512];
  int t = threadIdx.x;
  int v = (t < NB) ? blocksums[t] : 0;
  s[t] = v;
  __syncthreads();
  for (int off = 1; off < 512; off <<= 1) {
    int add = (t >= off) ? s[t - off] : 0;
    __syncthreads();
    s[t] += add;
    __syncthreads();
  }
  if (t < NB) blocksums[t] = s[t] - v;  // exclusive block offset
}

__global__ __launch_bounds__(256) void scanC_kernel(const int* __restrict__ scanned,
                                                    const int* __restrict__ deg,
                                                    const int* __restrict__ blocksums,
                                                    int* __restrict__ rowptr) {
  int i = blockIdx.x * 256 + threadIdx.x;
  if (i < NN) rowptr[i] = blocksums[blockIdx.x] + scanned[i] - deg[i];
  if (i == 0) rowptr[NN] = ETOT;
}

__global__ void scatter_kernel(const int* __restrict__ ei, const int* __restrict__ rowptr,
                               const int* __restrict__ rank, int* __restrict__ csr_src) {
  int i = blockIdx.x * blockDim.x + threadIdx.x;
  if (i >= ETOT) return;
  int src, dst;
  if (i < EE) { src = ei[i]; dst = ei[EE + i]; }
  else        { src = dst = i - EE; }
  csr_src[rowptr[dst] + rank[i]] = src;
}

// ---- layer-0 aggregate: one wave/node; stage 64 weights; consume 4 edges/iter (uint4) ----
__global__ __launch_bounds__(256) void agg0_kernel(const int* __restrict__ csr_src,
                                                   const int* __restrict__ rowptr,
                                                   const float* __restrict__ asrc0,
                                                   const float* __restrict__ adst0,
                                                   const unsigned* __restrict__ h0b,
                                                   const float* __restrict__ b0,
                                                   float* __restrict__ agg0) {
  __shared__ float ws[4][4][72];   // [wave][head][edge]
  __shared__ int   ss[4][64];
  int t = threadIdx.x;
  int lane = t & 63, wv = t >> 6;
  int n = blockIdx.x * 4 + wv;
  if (n >= NN) return;
  int start = rowptr[n], end = rowptr[n + 1];
  float4 ad = *(const float4*)&adst0[(size_t)n * 4];
  int q = lane >> 4, cp = lane & 15;     // channels 8*cp..8*cp+7; edge slot = eb + q
  int head = cp >> 2;
  float a0 = 0.f, a1 = 0.f, a2 = 0.f, a3 = 0.f, a4 = 0.f, a5 = 0.f, a6 = 0.f, a7 = 0.f;
  float d0 = 0.f, d1 = 0.f, d2 = 0.f, d3 = 0.f;

  for (int base = start; base < end; base += 64) {
    int cnt = min(64, end - base);
    if (lane < cnt) {
      int s = csr_src[base + lane];
      float4 as = *(const float4*)&asrc0[(size_t)s * 4];
      float w0 = __expf(lrelu(as.x + ad.x));
      float w1 = __expf(lrelu(as.y + ad.y));
      float w2 = __expf(lrelu(as.z + ad.z));
      float w3 = __expf(lrelu(as.w + ad.w));
      d0 += w0; d1 += w1; d2 += w2; d3 += w3;
      ss[wv][lane] = s;
      ws[wv][0][lane] = w0;
      ws[wv][1][lane] = w1;
      ws[wv][2][lane] = w2;
      ws[wv][3][lane] = w3;
    }
    __builtin_amdgcn_wave_barrier();
    for (int eb = 0; eb < cnt; eb += 4) {
      int e = eb + q;
      float w = (e < cnt) ? ws[wv][head][e] : 0.f;
      int ec = (e < cnt) ? e : cnt - 1;
      int s = ss[wv][ec];
      uint4 hv = *(const uint4*)&h0b[(size_t)s * 64 + cp * 4];
      a0 += w * bf16_lo(hv.x); a1 += w * bf16_hi(hv.x);
      a2 += w * bf16_lo(hv.y); a3 += w * bf16_hi(hv.y);
      a4 += w * bf16_lo(hv.z); a5 += w * bf16_hi(hv.z);
      a6 += w * bf16_lo(hv.w); a7 += w * bf16_hi(hv.w);
    }
    __builtin_amdgcn_wave_barrier();
  }
#pragma unroll
  for (int mk = 1; mk < 64; mk <<= 1) {
    d0 += __shfl_xor(d0, mk);
    d1 += __shfl_xor(d1, mk);
    d2 += __shfl_xor(d2, mk);
    d3 += __shfl_xor(d3, mk);
  }
  // cross-quarter reduce of channel accumulators
  a0 += __shfl_xor(a0, 16); a1 += __shfl_xor(a1, 16);
  a2 += __shfl_xor(a2, 16); a3 += __shfl_xor(a3, 16);
  a4 += __shfl_xor(a4, 16); a5 += __shfl_xor(a5, 16);
  a6 += __shfl_xor(a6, 16); a7 += __shfl_xor(a7, 16);
  a0 += __shfl_xor(a0, 32); a1 += __shfl_xor(a1, 32);
  a2 += __shfl_xor(a2, 32); a3 += __shfl_xor(a3, 32);
  a4 += __shfl_xor(a4, 32); a5 += __shfl_xor(a5, 32);
  a6 += __shfl_xor(a6, 32); a7 += __shfl_xor(a7, 32);
  if (q == 0) {
    float dh = head == 0 ? d0 : head == 1 ? d1 : head == 2 ? d2 : d3;
    float rd = 1.f / dh;
    int c = cp * 8;
    float4 o1, o2;
    o1.x = a0 * rd + b0[c + 0]; o1.y = a1 * rd + b0[c + 1];
    o1.z = a2 * rd + b0[c + 2]; o1.w = a3 * rd + b0[c + 3];
    o2.x = a4 * rd + b0[c + 4]; o2.y = a5 * rd + b0[c + 5];
    o2.z = a6 * rd + b0[c + 6]; o2.w = a7 * rd + b0[c + 7];
    *(float4*)&agg0[(size_t)n * 128 + c] = o1;
    *(float4*)&agg0[(size_t)n * 128 + c + 4] = o2;
  }
}

// ---------------- BatchNorm stats / finalize ----------------
__global__ __launch_bounds__(256) void bnstats_kernel(const float* __restrict__ agg0,
                                                      float* __restrict__ bnsum,
                                                      float* __restrict__ bnsq) {
  int t = threadIdx.x;
  int c = t & 127;
  int g = blockIdx.x * 2 + (t >> 7);
  float s = 0.f, q = 0.f;
  for (int r = g; r < NN; r += 1024) {
    float v = agg0[(size_t)r * 128 + c];
    s += v;
    q += v * v;
  }
  __shared__ float ls[256], lq[256];
  ls[t] = s; lq[t] = q;
  __syncthreads();
  if (t < 128) {
    s = ls[t] + ls[t + 128];
    q = lq[t] + lq[t + 128];
    atomicAdd(&bnsum[c], s);
    atomicAdd(&bnsq[c], q);
  }
}

__global__ void bnfinal_kernel(const float* __restrict__ bnsum, const float* __restrict__ bnsq,
                               const float* __restrict__ gamma, const float* __restrict__ beta,
                               float* __restrict__ bnscale, float* __restrict__ bnshift) {
  int c = threadIdx.x;  // 128 threads
  float mu = bnsum[c] / (float)NN;
  float var = bnsq[c] / (float)NN - mu * mu;
  float sc = gamma[c] / sqrtf(var + BNEPS);
  bnscale[c] = sc;
  bnshift[c] = beta[c] - mu * sc;
}

// ---- GEMM1 via MFMA: fused BN+ELU input transform, alpha1 epilogue, bf16 h1 ----
__global__ __launch_bounds__(256) void gemm1_kernel(const float* __restrict__ agg0,
                                                    const float* __restrict__ bnscale,
                                                    const float* __restrict__ bnshift,
                                                    const float* __restrict__ W1,
                                                    const float* __restrict__ a_src1,
                                                    const float* __restrict__ a_dst1,
                                                    unsigned* __restrict__ h1b,
                                                    float* __restrict__ asrc1,
                                                    float* __restrict__ adst1) {
  __shared__ __align__(16) unsigned As[64][68];  // bf16x2, row stride 68 u32
  __shared__ __align__(16) unsigned Wt[48][68];  // W1^T bf16x2: [col][k/2]
  int t = threadIdx.x;
  int rowbase = blockIdx.x * 64;

  for (int idx = t; idx < 48 * 64; idx += 256) {
    int c = idx >> 6, kp = idx & 63;
    float lo = (c < OD) ? W1[(size_t)(2 * kp) * OD + c] : 0.f;
    float hi = (c < OD) ? W1[(size_t)(2 * kp + 1) * OD + c] : 0.f;
    Wt[c][kp] = pack_bf16(lo, hi);
  }
  for (int idx = t; idx < 64 * 32; idx += 256) {
    int row = idx >> 5, k4 = idx & 31;
    int r = rowbase + row;
    int rc = r < NN ? r : NN - 1;
    int k = k4 * 4;
    float4 v  = *(const float4*)&agg0[(size_t)rc * 128 + k];
    float4 sc = *(const float4*)&bnscale[k];
    float4 sh = *(const float4*)&bnshift[k];
    float y0 = v.x * sc.x + sh.x;
    float y1 = v.y * sc.y + sh.y;
    float y2 = v.z * sc.z + sh.z;
    float y3 = v.w * sc.w + sh.w;
    y0 = y0 > 0.f ? y0 : expm1f(y0);
    y1 = y1 > 0.f ? y1 : expm1f(y1);
    y2 = y2 > 0.f ? y2 : expm1f(y2);
    y3 = y3 > 0.f ? y3 : expm1f(y3);
    As[row][k4 * 2]     = pack_bf16(y0, y1);
    As[row][k4 * 2 + 1] = pack_bf16(y2, y3);
  }
  __syncthreads();

  int lane = t & 63, w = t >> 6;
  int mrow = lane & 15, g = lane >> 4;
  f32x4 acc0 = {0.f, 0.f, 0.f, 0.f};
  f32x4 acc1 = {0.f, 0.f, 0.f, 0.f};
  f32x4 acc2 = {0.f, 0.f, 0.f, 0.f};
#pragma unroll
  for (int ks = 0; ks < 4; ks++) {
    bf16x8 a = *(const bf16x8*)&As[w * 16 + mrow][ks * 16 + g * 4];
    bf16x8 b0v = *(const bf16x8*)&Wt[mrow][ks * 16 + g * 4];
    bf16x8 b1v = *(const bf16x8*)&Wt[16 + mrow][ks * 16 + g * 4];
    bf16x8 b2v = *(const bf16x8*)&Wt[32 + mrow][ks * 16 + g * 4];
    acc0 = __builtin_amdgcn_mfma_f32_16x16x32_bf16(a, b0v, acc0, 0, 0, 0);
    acc1 = __builtin_amdgcn_mfma_f32_16x16x32_bf16(a, b1v, acc1, 0, 0, 0);
    acc2 = __builtin_amdgcn_mfma_f32_16x16x32_bf16(a, b2v, acc2, 0, 0, 0);
  }
  int col = lane & 15;
  float as0 = (col < OD)      ? a_src1[col]      : 0.f;
  float as1 = (16 + col < OD) ? a_src1[16 + col] : 0.f;
  float as2 = (32 + col < OD) ? a_src1[32 + col] : 0.f;
  float ad0 = (col < OD)      ? a_dst1[col]      : 0.f;
  float ad1 = (16 + col < OD) ? a_dst1[16 + col] : 0.f;
  float ad2 = (32 + col < OD) ? a_dst1[32 + col] : 0.f;
#pragma unroll
  for (int reg = 0; reg < 4; reg++) {
    int r = rowbase + w * 16 + g * 4 + reg;
    float v0 = acc0[reg], v1 = acc1[reg], v2 = acc2[reg];
    float ps = v0 * as0 + v1 * as1 + v2 * as2;
    float pd = v0 * ad0 + v1 * ad1 + v2 * ad2;
#pragma unroll
    for (int mk = 1; mk < 16; mk <<= 1) { ps += __shfl_xor(ps, mk); pd += __shfl_xor(pd, mk); }
    bool rok = r < NN;
    if ((lane & 15) == 0 && rok) { asrc1[r] = ps; adst1[r] = pd; }
    float n0 = __shfl_xor(v0, 1), n1 = __shfl_xor(v1, 1), n2 = __shfl_xor(v2, 1);
    if (!(col & 1) && rok) {
      h1b[(size_t)r * 20 + ((col) >> 1)]      = pack_bf16(v0, n0);
      h1b[(size_t)r * 20 + ((16 + col) >> 1)] = pack_bf16(v1, n1);
      if (32 + col < OD) h1b[(size_t)r * 20 + ((32 + col) >> 1)] = pack_bf16(v2, n2);
    }
  }
}

// ---- layer-1 aggregate: one wave/node; consume 3 edges/iter (60 lanes) ----
__global__ __launch_bounds__(256) void agg1_kernel(const int* __restrict__ csr_src,
                                                   const int* __restrict__ rowptr,
                                                   const float* __restrict__ asrc1,
                                                   const float* __restrict__ adst1,
                                                   const unsigned* __restrict__ h1b,
                                                   const float* __restrict__ b1,
                                                   float* __restrict__ out) {
  __shared__ float ws[4][64];
  __shared__ int   ss[4][64];
  int t = threadIdx.x;
  int lane = t & 63, wv = t >> 6;
  int n = blockIdx.x * 4 + wv;
  if (n >= NN) return;
  int start = rowptr[n], end = rowptr[n + 1];
  float ad = adst1[n];
  // lane -> (esub, chan) for lanes 0..59
  int esub = lane / 20;        // 0..2 (garbage 3 for lanes 60..63, guarded)
  int chan = lane - esub * 20;
  float dsum = 0.f, acc0 = 0.f, acc1 = 0.f;
  for (int base = start; base < end; base += 64) {
    int cnt = min(64, end - base);
    if (lane < cnt) {
      int s = csr_src[base + lane];
      float w = __expf(lrelu(asrc1[s] + ad));
      dsum += w;
      ss[wv][lane] = s;
      ws[wv][lane] = w;
    }
    __builtin_amdgcn_wave_barrier();
    if (lane < 60) {
      for (int e = esub; e < cnt; e += 3) {
        int s = ss[wv][e];
        float w = ws[wv][e];
        unsigned hv = h1b[(size_t)s * 20 + chan];
        acc0 += w * bf16_lo(hv);
        acc1 += w * bf16_hi(hv);
      }
    }
    __builtin_amdgcn_wave_barrier();
  }
#pragma unroll
  for (int mk = 1; mk < 64; mk <<= 1) dsum += __shfl_xor(dsum, mk);
  float rd = 1.f / dsum;
  // combine the 3 esub groups down to lanes 0..19
  float b0v = __shfl(acc0, lane + 20);
  float c0v = __shfl(acc0, lane + 40);
  float b1v = __shfl(acc1, lane + 20);
  float c1v = __shfl(acc1, lane + 40);
  if (lane < 20) {
    float2 o;
    o.x = (acc0 + b0v + c0v) * rd + b1[lane * 2];
    o.y = (acc1 + b1v + c1v) * rd + b1[lane * 2 + 1];
    *(float2*)&out[(size_t)n * 40 + lane * 2] = o;
  }
}

// ---------------- host launch ----------------
extern "C" void kernel_launch(void* const* d_in, const int* in_sizes, int n_in,
                              void* d_out, int out_size, void* d_ws, size_t ws_size,
                              hipStream_t stream) {
  const float* x       = (const float*)d_in[0];
  const int*   ei      = (const int*)d_in[1];
  const float* W0      = (const float*)d_in[2];
  const float* a_src0  = (const float*)d_in[3];
  const float* a_dst0  = (const float*)d_in[4];
  const float* b0      = (const float*)d_in[5];
  const float* gamma0  = (const float*)d_in[6];
  const float* beta0   = (const float*)d_in[7];
  const float* W1      = (const float*)d_in[8];
  const float* a_src1  = (const float*)d_in[9];
  const float* a_dst1  = (const float*)d_in[10];
  const float* b1      = (const float*)d_in[11];
  float* out = (float*)d_out;

  char* ws = (char*)d_ws;
  size_t off = 0;
  auto alloc = [&](size_t bytes) {
    void* p = ws + off;
    off += (bytes + 255) & ~(size_t)255;
    return p;
  };
  // zero-region first: deg, bnsum, bnsq (contiguous)
  int*   deg      = (int*)alloc((size_t)NN * 4);
  float* bnsum    = (float*)alloc(128 * 4);
  float* bnsq     = (float*)alloc(128 * 4);
  unsigned* h0b   = (unsigned*)alloc((size_t)NN * 64 * 4);   // bf16x2
  float* agg0     = (float*)alloc((size_t)NN * 128 * 4);
  unsigned* h1b   = (unsigned*)alloc((size_t)NN * 20 * 4);   // bf16x2
  float* asrc0    = (float*)alloc((size_t)NN * 4 * 4);
  float* adst0    = (float*)alloc((size_t)NN * 4 * 4);
  float* asrc1    = (float*)alloc((size_t)NN * 4);
  float* adst1    = (float*)alloc((size_t)NN * 4);
  float* bnscale  = (float*)alloc(128 * 4);
  float* bnshift  = (float*)alloc(128 * 4);
  int*   rowptr   = (int*)alloc((size_t)(NN + 1) * 4);
  int*   scanned  = (int*)alloc((size_t)NN * 4);
  int*   csr      = (int*)alloc((size_t)ETOT * 4);
  int*   rank     = (int*)alloc((size_t)ETOT * 4);
  int*   bsums    = (int*)alloc(512 * 4);
  unsigned* w0t   = (unsigned*)alloc(128 * 64 * 4);
  (void)ws_size; (void)in_sizes; (void)n_in; (void)out_size;

  size_t zbytes = (char*)(bnsq + 128) - (char*)deg;
  hipMemsetAsync(deg, 0, zbytes, stream);

  const int NB = (NN + 255) / 256;
  const int egrid = (ETOT + 255) / 256;

  w0pack_kernel<<<32, 256, 0, stream>>>(W0, w0t);
  gemm0_kernel<<<(NN + 63) / 64, 256, 0, stream>>>(x, w0t, a_src0, a_dst0, h0b, asrc0, adst0);
  degrank_kernel<<<egrid, 256, 0, stream>>>(ei, deg, rank);
  scanA_kernel<<<NB, 256, 0, stream>>>(deg, scanned, bsums);
  scanB_kernel<<<1, 512, 0, stream>>>(bsums, NB);
  scanC_kernel<<<NB, 256, 0, stream>>>(scanned, deg, bsums, rowptr);
  scatter_kernel<<<egrid, 256, 0, stream>>>(ei, rowptr, rank, csr);
  agg0_kernel<<<(NN + 3) / 4, 256, 0, stream>>>(csr, rowptr, asrc0, adst0, h0b, b0, agg0);
  bnstats_kernel<<<512, 256, 0, stream>>>(agg0, bnsum, bnsq);
  bnfinal_kernel<<<1, 128, 0, stream>>>(bnsum, bnsq, gamma0, beta0, bnscale, bnshift);
  gemm1_kernel<<<(NN + 63) / 64, 256, 0, stream>>>(agg0, bnscale, bnshift, W1, a_src1, a_dst1,
                                                   h1b, asrc1, adst1);
  agg1_kernel<<<(NN + 3) / 4, 256, 0, stream>>>(csr, rowptr, asrc1, adst1, h1b, b1, out);
}

// Round 6
// 339.906 us; speedup vs baseline: 2.4416x; 1.0206x over previous
//
#include <hip/hip_runtime.h>
#include <hip/hip_bf16.h>
#include <math.h>

#define NN   100000
#define EE   1600000
#define ETOT (NN + EE)
#define IND  128
#define HD   128    // HEADS*HID
#define OD   40
#define NEG  0.2f
#define BNEPS 1e-5f

typedef __attribute__((ext_vector_type(8))) short bf16x8;
typedef __attribute__((ext_vector_type(4))) float f32x4;

__device__ __forceinline__ float lrelu(float x) { return x > 0.f ? x : NEG * x; }

// pack two floats to bf16x2 (RNE)
__device__ __forceinline__ unsigned pack_bf16(float a, float b) {
  unsigned ua = __float_as_uint(a), ub = __float_as_uint(b);
  ua = (ua + 0x7fffu + ((ua >> 16) & 1u)) >> 16;
  ub = (ub + 0x7fffu + ((ub >> 16) & 1u)) >> 16;
  return ua | (ub << 16);
}
__device__ __forceinline__ float bf16_lo(unsigned v) { return __uint_as_float(v << 16); }
__device__ __forceinline__ float bf16_hi(unsigned v) { return __uint_as_float(v & 0xffff0000u); }

// ---- one-shot: pack W0 transposed to bf16x2  w0t[n][kp] = (W0[2kp][n], W0[2kp+1][n]) ----
__global__ __launch_bounds__(256) void w0pack_kernel(const float* __restrict__ W0,
                                                     unsigned* __restrict__ w0t) {
  int idx = blockIdx.x * 256 + threadIdx.x;
  if (idx >= 128 * 64) return;
  int n = idx & 127, kp = idx >> 7;   // coalesced reads along n
  float lo = W0[(size_t)(2 * kp) * 128 + n];
  float hi = W0[(size_t)(2 * kp + 1) * 128 + n];
  w0t[n * 64 + kp] = pack_bf16(lo, hi);
}

// ---- GEMM0 via MFMA: h0b = bf16(x @ W0), fused per-node/per-head alpha logits ----
__global__ __launch_bounds__(256) void gemm0_kernel(const float* __restrict__ x,
                                                    const unsigned* __restrict__ w0t,
                                                    const float* __restrict__ a_src0,
                                                    const float* __restrict__ a_dst0,
                                                    unsigned* __restrict__ h0b,
                                                    float* __restrict__ asrc0,
                                                    float* __restrict__ adst0) {
  __shared__ __align__(16) unsigned As[64][68];   // bf16x2 [row][k/2]
  __shared__ __align__(16) unsigned Wt[128][68];  // bf16x2 [col][k/2]
  int t = threadIdx.x;
  int rowbase = blockIdx.x * 64;
  for (int idx = t; idx < 128 * 64; idx += 256) {
    Wt[idx >> 6][idx & 63] = w0t[idx];
  }
  for (int idx = t; idx < 64 * 64; idx += 256) {
    int row = idx >> 6, kp = idx & 63;
    int r = rowbase + row;
    int rc = r < NN ? r : NN - 1;
    float2 v = *(const float2*)&x[(size_t)rc * 128 + kp * 2];
    As[row][kp] = pack_bf16(v.x, v.y);
  }
  __syncthreads();

  int lane = t & 63, w = t >> 6;
  int mrow = lane & 15, g = lane >> 4;
  f32x4 acc[8];
#pragma unroll
  for (int nt = 0; nt < 8; nt++) acc[nt] = (f32x4){0.f, 0.f, 0.f, 0.f};
#pragma unroll
  for (int ks = 0; ks < 4; ks++) {
    bf16x8 a = *(const bf16x8*)&As[w * 16 + mrow][ks * 16 + g * 4];
#pragma unroll
    for (int nt = 0; nt < 8; nt++) {
      bf16x8 b = *(const bf16x8*)&Wt[nt * 16 + mrow][ks * 16 + g * 4];
      acc[nt] = __builtin_amdgcn_mfma_f32_16x16x32_bf16(a, b, acc[nt], 0, 0, 0);
    }
  }
  // epilogue: C layout col = nt*16 + (lane&15), row = g*4 + reg
  int col = lane & 15;
  float as_[8], ad_[8];
#pragma unroll
  for (int nt = 0; nt < 8; nt++) {
    as_[nt] = a_src0[nt * 16 + col];
    ad_[nt] = a_dst0[nt * 16 + col];
  }
#pragma unroll
  for (int reg = 0; reg < 4; reg++) {
    int r = rowbase + w * 16 + g * 4 + reg;
    bool rok = r < NN;
    float hs0 = acc[0][reg] * as_[0] + acc[1][reg] * as_[1];
    float hs1 = acc[2][reg] * as_[2] + acc[3][reg] * as_[3];
    float hs2 = acc[4][reg] * as_[4] + acc[5][reg] * as_[5];
    float hs3 = acc[6][reg] * as_[6] + acc[7][reg] * as_[7];
    float hd0 = acc[0][reg] * ad_[0] + acc[1][reg] * ad_[1];
    float hd1 = acc[2][reg] * ad_[2] + acc[3][reg] * ad_[3];
    float hd2 = acc[4][reg] * ad_[4] + acc[5][reg] * ad_[5];
    float hd3 = acc[6][reg] * ad_[6] + acc[7][reg] * ad_[7];
#pragma unroll
    for (int mk = 1; mk < 16; mk <<= 1) {
      hs0 += __shfl_xor(hs0, mk); hs1 += __shfl_xor(hs1, mk);
      hs2 += __shfl_xor(hs2, mk); hs3 += __shfl_xor(hs3, mk);
      hd0 += __shfl_xor(hd0, mk); hd1 += __shfl_xor(hd1, mk);
      hd2 += __shfl_xor(hd2, mk); hd3 += __shfl_xor(hd3, mk);
    }
    if ((lane & 15) == 0 && rok) {
      asrc0[r * 4 + 0] = hs0; asrc0[r * 4 + 1] = hs1;
      asrc0[r * 4 + 2] = hs2; asrc0[r * 4 + 3] = hs3;
      adst0[r * 4 + 0] = hd0; adst0[r * 4 + 1] = hd1;
      adst0[r * 4 + 2] = hd2; adst0[r * 4 + 3] = hd3;
    }
#pragma unroll
    for (int nt = 0; nt < 8; nt++) {
      float v = acc[nt][reg];
      float nv = __shfl_xor(v, 1);
      if (!(col & 1) && rok) h0b[(size_t)r * 64 + nt * 8 + (col >> 1)] = pack_bf16(v, nv);
    }
  }
}

// ---------------- CSR build ----------------
__global__ void degrank_kernel(const int* __restrict__ ei, int* __restrict__ deg,
                               int* __restrict__ rank) {
  int i = blockIdx.x * blockDim.x + threadIdx.x;
  if (i >= ETOT) return;
  int dst = (i < EE) ? ei[EE + i] : (i - EE);
  rank[i] = atomicAdd(&deg[dst], 1);
}

__global__ __launch_bounds__(256) void scanA_kernel(const int* __restrict__ deg,
                                                    int* __restrict__ scanned,
                                                    int* __restrict__ blocksums) {
  __shared__ int s[256];
  int t = threadIdx.x;
  int i = blockIdx.x * 256 + t;
  int v = (i < NN) ? deg[i] : 0;
  s[t] = v;
  __syncthreads();
  for (int off = 1; off < 256; off <<= 1) {
    int add = (t >= off) ? s[t - off] : 0;
    __syncthreads();
    s[t] += add;
    __syncthreads();
  }
  if (i < NN) scanned[i] = s[t];
  if (t == 255) blocksums[blockIdx.x] = s[255];
}

__global__ __launch_bounds__(512) void scanB_kernel(int* __restrict__ blocksums, int NB) {
  __shared__ int s[512];
  int t = threadIdx.x;
  int v = (t < NB) ? blocksums[t] : 0;
  s[t] = v;
  __syncthreads();
  for (int off = 1; off < 512; off <<= 1) {
    int add = (t >= off) ? s[t - off] : 0;
    __syncthreads();
    s[t] += add;
    __syncthreads();
  }
  if (t < NB) blocksums[t] = s[t] - v;  // exclusive block offset
}

__global__ __launch_bounds__(256) void scanC_kernel(const int* __restrict__ scanned,
                                                    const int* __restrict__ deg,
                                                    const int* __restrict__ blocksums,
                                                    int* __restrict__ rowptr) {
  int i = blockIdx.x * 256 + threadIdx.x;
  if (i < NN) rowptr[i] = blocksums[blockIdx.x] + scanned[i] - deg[i];
  if (i == 0) rowptr[NN] = ETOT;
}

__global__ void scatter_kernel(const int* __restrict__ ei, const int* __restrict__ rowptr,
                               const int* __restrict__ rank, int* __restrict__ csr_src) {
  int i = blockIdx.x * blockDim.x + threadIdx.x;
  if (i >= ETOT) return;
  int src, dst;
  if (i < EE) { src = ei[i]; dst = ei[EE + i]; }
  else        { src = dst = i - EE; }
  csr_src[rowptr[dst] + rank[i]] = src;
}

// ---- layer-0 aggregate: 16 lanes per node, 4 nodes/wave, 16 nodes/block ----
// Lane p owns channels 8p..8p+7 exclusively (no acc cross-lane reduce).
// Consume 4 edges in flight per lane (4 independent uint4 gathers).
__global__ __launch_bounds__(256) void agg0_kernel(const int* __restrict__ csr_src,
                                                   const int* __restrict__ rowptr,
                                                   const float* __restrict__ asrc0,
                                                   const float* __restrict__ adst0,
                                                   const unsigned* __restrict__ h0b,
                                                   const float* __restrict__ b0,
                                                   unsigned* __restrict__ agg0b) {
  __shared__ float ws[16][4][17];   // [group][head][edge]
  __shared__ int   ss[16][16];
  int t = threadIdx.x;
  int grp = t >> 4;        // node group 0..15
  int p   = t & 15;        // lane within group; owns channels 8p..8p+7
  int n = blockIdx.x * 16 + grp;
  if (n >= NN) return;
  int start = rowptr[n], end = rowptr[n + 1];
  float4 ad = *(const float4*)&adst0[(size_t)n * 4];
  int head = p >> 2;
  float a0 = 0.f, a1 = 0.f, a2 = 0.f, a3 = 0.f, a4 = 0.f, a5 = 0.f, a6 = 0.f, a7 = 0.f;
  float d0 = 0.f, d1 = 0.f, d2 = 0.f, d3 = 0.f;

  for (int base = start; base < end; base += 16) {
    int cnt = min(16, end - base);
    if (p < cnt) {
      int s = csr_src[base + p];
      float4 as = *(const float4*)&asrc0[(size_t)s * 4];
      float w0 = __expf(lrelu(as.x + ad.x));
      float w1 = __expf(lrelu(as.y + ad.y));
      float w2 = __expf(lrelu(as.z + ad.z));
      float w3 = __expf(lrelu(as.w + ad.w));
      d0 += w0; d1 += w1; d2 += w2; d3 += w3;
      ss[grp][p] = s;
      ws[grp][0][p] = w0;
      ws[grp][1][p] = w1;
      ws[grp][2][p] = w2;
      ws[grp][3][p] = w3;
    }
    __builtin_amdgcn_wave_barrier();
    for (int eb = 0; eb < cnt; eb += 4) {
      int e0 = eb, e1 = eb + 1, e2 = eb + 2, e3 = eb + 3;
      float w0 = ws[grp][head][e0];                       // e0 < cnt always
      float w1 = (e1 < cnt) ? ws[grp][head][e1] : 0.f;
      float w2 = (e2 < cnt) ? ws[grp][head][e2] : 0.f;
      float w3 = (e3 < cnt) ? ws[grp][head][e3] : 0.f;
      int s0 = ss[grp][e0];
      int s1 = ss[grp][(e1 < cnt) ? e1 : e0];
      int s2 = ss[grp][(e2 < cnt) ? e2 : e0];
      int s3 = ss[grp][(e3 < cnt) ? e3 : e0];
      uint4 h0v = *(const uint4*)&h0b[(size_t)s0 * 64 + p * 4];
      uint4 h1v = *(const uint4*)&h0b[(size_t)s1 * 64 + p * 4];
      uint4 h2v = *(const uint4*)&h0b[(size_t)s2 * 64 + p * 4];
      uint4 h3v = *(const uint4*)&h0b[(size_t)s3 * 64 + p * 4];
      a0 += w0 * bf16_lo(h0v.x); a1 += w0 * bf16_hi(h0v.x);
      a2 += w0 * bf16_lo(h0v.y); a3 += w0 * bf16_hi(h0v.y);
      a4 += w0 * bf16_lo(h0v.z); a5 += w0 * bf16_hi(h0v.z);
      a6 += w0 * bf16_lo(h0v.w); a7 += w0 * bf16_hi(h0v.w);
      a0 += w1 * bf16_lo(h1v.x); a1 += w1 * bf16_hi(h1v.x);
      a2 += w1 * bf16_lo(h1v.y); a3 += w1 * bf16_hi(h1v.y);
      a4 += w1 * bf16_lo(h1v.z); a5 += w1 * bf16_hi(h1v.z);
      a6 += w1 * bf16_lo(h1v.w); a7 += w1 * bf16_hi(h1v.w);
      a0 += w2 * bf16_lo(h2v.x); a1 += w2 * bf16_hi(h2v.x);
      a2 += w2 * bf16_lo(h2v.y); a3 += w2 * bf16_hi(h2v.y);
      a4 += w2 * bf16_lo(h2v.z); a5 += w2 * bf16_hi(h2v.z);
      a6 += w2 * bf16_lo(h2v.w); a7 += w2 * bf16_hi(h2v.w);
      a0 += w3 * bf16_lo(h3v.x); a1 += w3 * bf16_hi(h3v.x);
      a2 += w3 * bf16_lo(h3v.y); a3 += w3 * bf16_hi(h3v.y);
      a4 += w3 * bf16_lo(h3v.z); a5 += w3 * bf16_hi(h3v.z);
      a6 += w3 * bf16_lo(h3v.w); a7 += w3 * bf16_hi(h3v.w);
    }
    __builtin_amdgcn_wave_barrier();
  }
  // d reduce within 16-lane group
#pragma unroll
  for (int mk = 1; mk < 16; mk <<= 1) {
    d0 += __shfl_xor(d0, mk);
    d1 += __shfl_xor(d1, mk);
    d2 += __shfl_xor(d2, mk);
    d3 += __shfl_xor(d3, mk);
  }
  float dh = head == 0 ? d0 : head == 1 ? d1 : head == 2 ? d2 : d3;
  float rd = 1.f / dh;
  int c = p * 8;
  float4 b1v = *(const float4*)&b0[c];
  float4 b2v = *(const float4*)&b0[c + 4];
  float o0 = a0 * rd + b1v.x, o1 = a1 * rd + b1v.y;
  float o2 = a2 * rd + b1v.z, o3 = a3 * rd + b1v.w;
  float o4 = a4 * rd + b2v.x, o5 = a5 * rd + b2v.y;
  float o6 = a6 * rd + b2v.z, o7 = a7 * rd + b2v.w;
  uint4 o;
  o.x = pack_bf16(o0, o1);
  o.y = pack_bf16(o2, o3);
  o.z = pack_bf16(o4, o5);
  o.w = pack_bf16(o6, o7);
  *(uint4*)&agg0b[(size_t)n * 64 + p * 4] = o;
}

// ---------------- BatchNorm stats (bf16 input) / finalize ----------------
__global__ __launch_bounds__(256) void bnstats_kernel(const unsigned* __restrict__ agg0b,
                                                      float* __restrict__ bnsum,
                                                      float* __restrict__ bnsq) {
  int t = threadIdx.x;
  int c2 = t & 63;         // u32 index -> channels 2*c2, 2*c2+1
  int rg = t >> 6;         // 0..3
  float sl = 0.f, sh = 0.f, ql = 0.f, qh = 0.f;
  for (int r = blockIdx.x * 4 + rg; r < NN; r += 2048) {
    unsigned u = agg0b[(size_t)r * 64 + c2];
    float lo = bf16_lo(u), hi = bf16_hi(u);
    sl += lo; sh += hi;
    ql += lo * lo; qh += hi * hi;
  }
  __shared__ float L1[256], L2[256], L3[256], L4[256];
  L1[t] = sl; L2[t] = sh; L3[t] = ql; L4[t] = qh;
  __syncthreads();
  if (t < 64) {
    sl = L1[t] + L1[t + 64] + L1[t + 128] + L1[t + 192];
    sh = L2[t] + L2[t + 64] + L2[t + 128] + L2[t + 192];
    ql = L3[t] + L3[t + 64] + L3[t + 128] + L3[t + 192];
    qh = L4[t] + L4[t + 64] + L4[t + 128] + L4[t + 192];
    atomicAdd(&bnsum[2 * t], sl);
    atomicAdd(&bnsum[2 * t + 1], sh);
    atomicAdd(&bnsq[2 * t], ql);
    atomicAdd(&bnsq[2 * t + 1], qh);
  }
}

__global__ void bnfinal_kernel(const float* __restrict__ bnsum, const float* __restrict__ bnsq,
                               const float* __restrict__ gamma, const float* __restrict__ beta,
                               float* __restrict__ bnscale, float* __restrict__ bnshift) {
  int c = threadIdx.x;  // 128 threads
  float mu = bnsum[c] / (float)NN;
  float var = bnsq[c] / (float)NN - mu * mu;
  float sc = gamma[c] / sqrtf(var + BNEPS);
  bnscale[c] = sc;
  bnshift[c] = beta[c] - mu * sc;
}

// ---- GEMM1 via MFMA: bf16 input + fused BN+ELU, alpha1 epilogue, bf16 h1 ----
__global__ __launch_bounds__(256) void gemm1_kernel(const unsigned* __restrict__ agg0b,
                                                    const float* __restrict__ bnscale,
                                                    const float* __restrict__ bnshift,
                                                    const float* __restrict__ W1,
                                                    const float* __restrict__ a_src1,
                                                    const float* __restrict__ a_dst1,
                                                    unsigned* __restrict__ h1b,
                                                    float* __restrict__ asrc1,
                                                    float* __restrict__ adst1) {
  __shared__ __align__(16) unsigned As[64][68];  // bf16x2, row stride 68 u32
  __shared__ __align__(16) unsigned Wt[48][68];  // W1^T bf16x2: [col][k/2]
  int t = threadIdx.x;
  int rowbase = blockIdx.x * 64;

  for (int idx = t; idx < 48 * 64; idx += 256) {
    int c = idx >> 6, kp = idx & 63;
    float lo = (c < OD) ? W1[(size_t)(2 * kp) * OD + c] : 0.f;
    float hi = (c < OD) ? W1[(size_t)(2 * kp + 1) * OD + c] : 0.f;
    Wt[c][kp] = pack_bf16(lo, hi);
  }
  for (int idx = t; idx < 64 * 16; idx += 256) {
    int row = idx >> 4, c4 = idx & 15;
    int r = rowbase + row;
    int rc = r < NN ? r : NN - 1;
    int k = c4 * 8;
    uint4 hv = *(const uint4*)&agg0b[(size_t)rc * 64 + c4 * 4];
    float4 sc1 = *(const float4*)&bnscale[k];
    float4 sc2 = *(const float4*)&bnscale[k + 4];
    float4 sh1 = *(const float4*)&bnshift[k];
    float4 sh2 = *(const float4*)&bnshift[k + 4];
    float y0 = bf16_lo(hv.x) * sc1.x + sh1.x;
    float y1 = bf16_hi(hv.x) * sc1.y + sh1.y;
    float y2 = bf16_lo(hv.y) * sc1.z + sh1.z;
    float y3 = bf16_hi(hv.y) * sc1.w + sh1.w;
    float y4 = bf16_lo(hv.z) * sc2.x + sh2.x;
    float y5 = bf16_hi(hv.z) * sc2.y + sh2.y;
    float y6 = bf16_lo(hv.w) * sc2.z + sh2.z;
    float y7 = bf16_hi(hv.w) * sc2.w + sh2.w;
    y0 = y0 > 0.f ? y0 : expm1f(y0);
    y1 = y1 > 0.f ? y1 : expm1f(y1);
    y2 = y2 > 0.f ? y2 : expm1f(y2);
    y3 = y3 > 0.f ? y3 : expm1f(y3);
    y4 = y4 > 0.f ? y4 : expm1f(y4);
    y5 = y5 > 0.f ? y5 : expm1f(y5);
    y6 = y6 > 0.f ? y6 : expm1f(y6);
    y7 = y7 > 0.f ? y7 : expm1f(y7);
    As[row][c4 * 4 + 0] = pack_bf16(y0, y1);
    As[row][c4 * 4 + 1] = pack_bf16(y2, y3);
    As[row][c4 * 4 + 2] = pack_bf16(y4, y5);
    As[row][c4 * 4 + 3] = pack_bf16(y6, y7);
  }
  __syncthreads();

  int lane = t & 63, w = t >> 6;
  int mrow = lane & 15, g = lane >> 4;
  f32x4 acc0 = {0.f, 0.f, 0.f, 0.f};
  f32x4 acc1 = {0.f, 0.f, 0.f, 0.f};
  f32x4 acc2 = {0.f, 0.f, 0.f, 0.f};
#pragma unroll
  for (int ks = 0; ks < 4; ks++) {
    bf16x8 a = *(const bf16x8*)&As[w * 16 + mrow][ks * 16 + g * 4];
    bf16x8 b0v = *(const bf16x8*)&Wt[mrow][ks * 16 + g * 4];
    bf16x8 b1v = *(const bf16x8*)&Wt[16 + mrow][ks * 16 + g * 4];
    bf16x8 b2v = *(const bf16x8*)&Wt[32 + mrow][ks * 16 + g * 4];
    acc0 = __builtin_amdgcn_mfma_f32_16x16x32_bf16(a, b0v, acc0, 0, 0, 0);
    acc1 = __builtin_amdgcn_mfma_f32_16x16x32_bf16(a, b1v, acc1, 0, 0, 0);
    acc2 = __builtin_amdgcn_mfma_f32_16x16x32_bf16(a, b2v, acc2, 0, 0, 0);
  }
  int col = lane & 15;
  float as0 = (col < OD)      ? a_src1[col]      : 0.f;
  float as1 = (16 + col < OD) ? a_src1[16 + col] : 0.f;
  float as2 = (32 + col < OD) ? a_src1[32 + col] : 0.f;
  float ad0 = (col < OD)      ? a_dst1[col]      : 0.f;
  float ad1 = (16 + col < OD) ? a_dst1[16 + col] : 0.f;
  float ad2 = (32 + col < OD) ? a_dst1[32 + col] : 0.f;
#pragma unroll
  for (int reg = 0; reg < 4; reg++) {
    int r = rowbase + w * 16 + g * 4 + reg;
    float v0 = acc0[reg], v1 = acc1[reg], v2 = acc2[reg];
    float ps = v0 * as0 + v1 * as1 + v2 * as2;
    float pd = v0 * ad0 + v1 * ad1 + v2 * ad2;
#pragma unroll
    for (int mk = 1; mk < 16; mk <<= 1) { ps += __shfl_xor(ps, mk); pd += __shfl_xor(pd, mk); }
    bool rok = r < NN;
    if ((lane & 15) == 0 && rok) { asrc1[r] = ps; adst1[r] = pd; }
    float n0 = __shfl_xor(v0, 1), n1 = __shfl_xor(v1, 1), n2 = __shfl_xor(v2, 1);
    if (!(col & 1) && rok) {
      h1b[(size_t)r * 20 + ((col) >> 1)]      = pack_bf16(v0, n0);
      h1b[(size_t)r * 20 + ((16 + col) >> 1)] = pack_bf16(v1, n1);
      if (32 + col < OD) h1b[(size_t)r * 20 + ((32 + col) >> 1)] = pack_bf16(v2, n2);
    }
  }
}

// ---- layer-1 aggregate: one wave/node; consume 3 edges/iter (60 lanes) ----
__global__ __launch_bounds__(256) void agg1_kernel(const int* __restrict__ csr_src,
                                                   const int* __restrict__ rowptr,
                                                   const float* __restrict__ asrc1,
                                                   const float* __restrict__ adst1,
                                                   const unsigned* __restrict__ h1b,
                                                   const float* __restrict__ b1,
                                                   float* __restrict__ out) {
  __shared__ float ws[4][64];
  __shared__ int   ss[4][64];
  int t = threadIdx.x;
  int lane = t & 63, wv = t >> 6;
  int n = blockIdx.x * 4 + wv;
  if (n >= NN) return;
  int start = rowptr[n], end = rowptr[n + 1];
  float ad = adst1[n];
  int esub = lane / 20;        // 0..2 for lanes 0..59
  int chan = lane - esub * 20;
  float dsum = 0.f, acc0 = 0.f, acc1 = 0.f;
  for (int base = start; base < end; base += 64) {
    int cnt = min(64, end - base);
    if (lane < cnt) {
      int s = csr_src[base + lane];
      float w = __expf(lrelu(asrc1[s] + ad));
      dsum += w;
      ss[wv][lane] = s;
      ws[wv][lane] = w;
    }
    __builtin_amdgcn_wave_barrier();
    if (lane < 60) {
      for (int e = esub; e < cnt; e += 3) {
        int s = ss[wv][e];
        float w = ws[wv][e];
        unsigned hv = h1b[(size_t)s * 20 + chan];
        acc0 += w * bf16_lo(hv);
        acc1 += w * bf16_hi(hv);
      }
    }
    __builtin_amdgcn_wave_barrier();
  }
#pragma unroll
  for (int mk = 1; mk < 64; mk <<= 1) dsum += __shfl_xor(dsum, mk);
  float rd = 1.f / dsum;
  float b0v = __shfl(acc0, lane + 20);
  float c0v = __shfl(acc0, lane + 40);
  float b1v = __shfl(acc1, lane + 20);
  float c1v = __shfl(acc1, lane + 40);
  if (lane < 20) {
    float2 o;
    o.x = (acc0 + b0v + c0v) * rd + b1[lane * 2];
    o.y = (acc1 + b1v + c1v) * rd + b1[lane * 2 + 1];
    *(float2*)&out[(size_t)n * 40 + lane * 2] = o;
  }
}

// ---------------- host launch ----------------
extern "C" void kernel_launch(void* const* d_in, const int* in_sizes, int n_in,
                              void* d_out, int out_size, void* d_ws, size_t ws_size,
                              hipStream_t stream) {
  const float* x       = (const float*)d_in[0];
  const int*   ei      = (const int*)d_in[1];
  const float* W0      = (const float*)d_in[2];
  const float* a_src0  = (const float*)d_in[3];
  const float* a_dst0  = (const float*)d_in[4];
  const float* b0      = (const float*)d_in[5];
  const float* gamma0  = (const float*)d_in[6];
  const float* beta0   = (const float*)d_in[7];
  const float* W1      = (const float*)d_in[8];
  const float* a_src1  = (const float*)d_in[9];
  const float* a_dst1  = (const float*)d_in[10];
  const float* b1      = (const float*)d_in[11];
  float* out = (float*)d_out;

  char* ws = (char*)d_ws;
  size_t off = 0;
  auto alloc = [&](size_t bytes) {
    void* p = ws + off;
    off += (bytes + 255) & ~(size_t)255;
    return p;
  };
  // zero-region first: deg, bnsum, bnsq (contiguous)
  int*   deg      = (int*)alloc((size_t)NN * 4);
  float* bnsum    = (float*)alloc(128 * 4);
  float* bnsq     = (float*)alloc(128 * 4);
  unsigned* h0b   = (unsigned*)alloc((size_t)NN * 64 * 4);   // bf16x2
  unsigned* agg0b = (unsigned*)alloc((size_t)NN * 64 * 4);   // bf16x2
  unsigned* h1b   = (unsigned*)alloc((size_t)NN * 20 * 4);   // bf16x2
  float* asrc0    = (float*)alloc((size_t)NN * 4 * 4);
  float* adst0    = (float*)alloc((size_t)NN * 4 * 4);
  float* asrc1    = (float*)alloc((size_t)NN * 4);
  float* adst1    = (float*)alloc((size_t)NN * 4);
  float* bnscale  = (float*)alloc(128 * 4);
  float* bnshift  = (float*)alloc(128 * 4);
  int*   rowptr   = (int*)alloc((size_t)(NN + 1) * 4);
  int*   scanned  = (int*)alloc((size_t)NN * 4);
  int*   csr      = (int*)alloc((size_t)ETOT * 4);
  int*   rank     = (int*)alloc((size_t)ETOT * 4);
  int*   bsums    = (int*)alloc(512 * 4);
  unsigned* w0t   = (unsigned*)alloc(128 * 64 * 4);
  (void)ws_size; (void)in_sizes; (void)n_in; (void)out_size;

  size_t zbytes = (char*)(bnsq + 128) - (char*)deg;
  hipMemsetAsync(deg, 0, zbytes, stream);

  const int NB = (NN + 255) / 256;
  const int egrid = (ETOT + 255) / 256;

  w0pack_kernel<<<32, 256, 0, stream>>>(W0, w0t);
  gemm0_kernel<<<(NN + 63) / 64, 256, 0, stream>>>(x, w0t, a_src0, a_dst0, h0b, asrc0, adst0);
  degrank_kernel<<<egrid, 256, 0, stream>>>(ei, deg, rank);
  scanA_kernel<<<NB, 256, 0, stream>>>(deg, scanned, bsums);
  scanB_kernel<<<1, 512, 0, stream>>>(bsums, NB);
  scanC_kernel<<<NB, 256, 0, stream>>>(scanned, deg, bsums, rowptr);
  scatter_kernel<<<egrid, 256, 0, stream>>>(ei, rowptr, rank, csr);
  agg0_kernel<<<(NN + 15) / 16, 256, 0, stream>>>(csr, rowptr, asrc0, adst0, h0b, b0, agg0b);
  bnstats_kernel<<<512, 256, 0, stream>>>(agg0b, bnsum, bnsq);
  bnfinal_kernel<<<1, 128, 0, stream>>>(bnsum, bnsq, gamma0, beta0, bnscale, bnshift);
  gemm1_kernel<<<(NN + 63) / 64, 256, 0, stream>>>(agg0b, bnscale, bnshift, W1, a_src1, a_dst1,
                                                   h1b, asrc1, adst1);
  agg1_kernel<<<(NN + 3) / 4, 256, 0, stream>>>(csr, rowptr, asrc1, adst1, h1b, b1, out);
}

// Round 7
// 330.844 us; speedup vs baseline: 2.5085x; 1.0274x over previous
//
#include <hip/hip_runtime.h>
#include <hip/hip_bf16.h>
#include <math.h>

#define NN   100000
#define EE   1600000
#define ETOT (NN + EE)
#define IND  128
#define HD   128    // HEADS*HID
#define OD   40
#define NEG  0.2f
#define BNEPS 1e-5f

typedef __attribute__((ext_vector_type(8))) short bf16x8;
typedef __attribute__((ext_vector_type(4))) float f32x4;

__device__ __forceinline__ float lrelu(float x) { return x > 0.f ? x : NEG * x; }

// pack two floats to bf16x2 (RNE)
__device__ __forceinline__ unsigned pack_bf16(float a, float b) {
  unsigned ua = __float_as_uint(a), ub = __float_as_uint(b);
  ua = (ua + 0x7fffu + ((ua >> 16) & 1u)) >> 16;
  ub = (ub + 0x7fffu + ((ub >> 16) & 1u)) >> 16;
  return ua | (ub << 16);
}
__device__ __forceinline__ float bf16_lo(unsigned v) { return __uint_as_float(v << 16); }
__device__ __forceinline__ float bf16_hi(unsigned v) { return __uint_as_float(v & 0xffff0000u); }

// ---- one-shot: pack W0 transposed to bf16x2 ----
__global__ __launch_bounds__(256) void w0pack_kernel(const float* __restrict__ W0,
                                                     unsigned* __restrict__ w0t) {
  int idx = blockIdx.x * 256 + threadIdx.x;
  if (idx >= 128 * 64) return;
  int n = idx & 127, kp = idx >> 7;
  float lo = W0[(size_t)(2 * kp) * 128 + n];
  float hi = W0[(size_t)(2 * kp + 1) * 128 + n];
  w0t[n * 64 + kp] = pack_bf16(lo, hi);
}

// ---- GEMM0 via MFMA + fused alpha logits + FUSED degrank (edge grid-stride) ----
__global__ __launch_bounds__(256) void gemm0_kernel(const float* __restrict__ x,
                                                    const unsigned* __restrict__ w0t,
                                                    const float* __restrict__ a_src0,
                                                    const float* __restrict__ a_dst0,
                                                    unsigned* __restrict__ h0b,
                                                    float* __restrict__ asrc0,
                                                    float* __restrict__ adst0,
                                                    const int* __restrict__ ei,
                                                    int* __restrict__ deg,
                                                    int* __restrict__ rank) {
  __shared__ __align__(16) unsigned As[64][68];   // bf16x2 [row][k/2]
  __shared__ __align__(16) unsigned Wt[128][68];  // bf16x2 [col][k/2]
  int t = threadIdx.x;
  int rowbase = blockIdx.x * 64;
  for (int idx = t; idx < 128 * 64; idx += 256) {
    Wt[idx >> 6][idx & 63] = w0t[idx];
  }
  for (int idx = t; idx < 64 * 64; idx += 256) {
    int row = idx >> 6, kp = idx & 63;
    int r = rowbase + row;
    int rc = r < NN ? r : NN - 1;
    float2 v = *(const float2*)&x[(size_t)rc * 128 + kp * 2];
    As[row][kp] = pack_bf16(v.x, v.y);
  }
  __syncthreads();

  int lane = t & 63, w = t >> 6;
  int mrow = lane & 15, g = lane >> 4;
  f32x4 acc[8];
#pragma unroll
  for (int nt = 0; nt < 8; nt++) acc[nt] = (f32x4){0.f, 0.f, 0.f, 0.f};
#pragma unroll
  for (int ks = 0; ks < 4; ks++) {
    bf16x8 a = *(const bf16x8*)&As[w * 16 + mrow][ks * 16 + g * 4];
#pragma unroll
    for (int nt = 0; nt < 8; nt++) {
      bf16x8 b = *(const bf16x8*)&Wt[nt * 16 + mrow][ks * 16 + g * 4];
      acc[nt] = __builtin_amdgcn_mfma_f32_16x16x32_bf16(a, b, acc[nt], 0, 0, 0);
    }
  }
  int col = lane & 15;
  float as_[8], ad_[8];
#pragma unroll
  for (int nt = 0; nt < 8; nt++) {
    as_[nt] = a_src0[nt * 16 + col];
    ad_[nt] = a_dst0[nt * 16 + col];
  }
#pragma unroll
  for (int reg = 0; reg < 4; reg++) {
    int r = rowbase + w * 16 + g * 4 + reg;
    bool rok = r < NN;
    float hs0 = acc[0][reg] * as_[0] + acc[1][reg] * as_[1];
    float hs1 = acc[2][reg] * as_[2] + acc[3][reg] * as_[3];
    float hs2 = acc[4][reg] * as_[4] + acc[5][reg] * as_[5];
    float hs3 = acc[6][reg] * as_[6] + acc[7][reg] * as_[7];
    float hd0 = acc[0][reg] * ad_[0] + acc[1][reg] * ad_[1];
    float hd1 = acc[2][reg] * ad_[2] + acc[3][reg] * ad_[3];
    float hd2 = acc[4][reg] * ad_[4] + acc[5][reg] * ad_[5];
    float hd3 = acc[6][reg] * ad_[6] + acc[7][reg] * ad_[7];
#pragma unroll
    for (int mk = 1; mk < 16; mk <<= 1) {
      hs0 += __shfl_xor(hs0, mk); hs1 += __shfl_xor(hs1, mk);
      hs2 += __shfl_xor(hs2, mk); hs3 += __shfl_xor(hs3, mk);
      hd0 += __shfl_xor(hd0, mk); hd1 += __shfl_xor(hd1, mk);
      hd2 += __shfl_xor(hd2, mk); hd3 += __shfl_xor(hd3, mk);
    }
    if ((lane & 15) == 0 && rok) {
      asrc0[r * 4 + 0] = hs0; asrc0[r * 4 + 1] = hs1;
      asrc0[r * 4 + 2] = hs2; asrc0[r * 4 + 3] = hs3;
      adst0[r * 4 + 0] = hd0; adst0[r * 4 + 1] = hd1;
      adst0[r * 4 + 2] = hd2; adst0[r * 4 + 3] = hd3;
    }
#pragma unroll
    for (int nt = 0; nt < 8; nt++) {
      float v = acc[nt][reg];
      float nv = __shfl_xor(v, 1);
      if (!(col & 1) && rok) h0b[(size_t)r * 64 + nt * 8 + (col >> 1)] = pack_bf16(v, nv);
    }
  }
  // fused degrank: grid-stride over edges; atomic latency hides under other waves' GEMM
  int gtid = blockIdx.x * 256 + t;
  int gstride = gridDim.x * 256;
  for (int i = gtid; i < ETOT; i += gstride) {
    int dst = (i < EE) ? ei[EE + i] : (i - EE);
    rank[i] = atomicAdd(&deg[dst], 1);
  }
}

// ---------------- CSR build ----------------
__global__ __launch_bounds__(256) void scanA_kernel(const int* __restrict__ deg,
                                                    int* __restrict__ scanned,
                                                    int* __restrict__ blocksums) {
  __shared__ int s[256];
  int t = threadIdx.x;
  int i = blockIdx.x * 256 + t;
  int v = (i < NN) ? deg[i] : 0;
  s[t] = v;
  __syncthreads();
  for (int off = 1; off < 256; off <<= 1) {
    int add = (t >= off) ? s[t - off] : 0;
    __syncthreads();
    s[t] += add;
    __syncthreads();
  }
  if (i < NN) scanned[i] = s[t];
  if (t == 255) blocksums[blockIdx.x] = s[255];
}

__global__ __launch_bounds__(512) void scanB_kernel(int* __restrict__ blocksums, int NB) {
  __shared__ int s[512];
  int t = threadIdx.x;
  int v = (t < NB) ? blocksums[t] : 0;
  s[t] = v;
  __syncthreads();
  for (int off = 1; off < 512; off <<= 1) {
    int add = (t >= off) ? s[t - off] : 0;
    __syncthreads();
    s[t] += add;
    __syncthreads();
  }
  if (t < NB) blocksums[t] = s[t] - v;  // exclusive block offset
}

__global__ __launch_bounds__(256) void scanC_kernel(const int* __restrict__ scanned,
                                                    const int* __restrict__ deg,
                                                    const int* __restrict__ blocksums,
                                                    int* __restrict__ rowptr) {
  int i = blockIdx.x * 256 + threadIdx.x;
  if (i < NN) rowptr[i] = blocksums[blockIdx.x] + scanned[i] - deg[i];
  if (i == 0) rowptr[NN] = ETOT;
}

__global__ void scatter_kernel(const int* __restrict__ ei, const int* __restrict__ rowptr,
                               const int* __restrict__ rank, int* __restrict__ csr_src) {
  int i = blockIdx.x * blockDim.x + threadIdx.x;
  if (i >= ETOT) return;
  int src, dst;
  if (i < EE) { src = ei[i]; dst = ei[EE + i]; }
  else        { src = dst = i - EE; }
  csr_src[rowptr[dst] + rank[i]] = src;
}

// ---- layer-0 aggregate: 16 lanes/node; 16-deep gather pipeline on full chunks ----
__global__ __launch_bounds__(256) void agg0_kernel(const int* __restrict__ csr_src,
                                                   const int* __restrict__ rowptr,
                                                   const float* __restrict__ asrc0,
                                                   const float* __restrict__ adst0,
                                                   const unsigned* __restrict__ h0b,
                                                   const float* __restrict__ b0,
                                                   unsigned* __restrict__ agg0b) {
  __shared__ float ws[16][4][17];   // [group][head][edge]
  __shared__ int   ss[16][16];
  int t = threadIdx.x;
  int grp = t >> 4;        // node group 0..15
  int p   = t & 15;        // owns channels 8p..8p+7
  int n = blockIdx.x * 16 + grp;
  if (n >= NN) return;
  int start = rowptr[n], end = rowptr[n + 1];
  float4 ad = *(const float4*)&adst0[(size_t)n * 4];
  int head = p >> 2;
  float a0 = 0.f, a1 = 0.f, a2 = 0.f, a3 = 0.f, a4 = 0.f, a5 = 0.f, a6 = 0.f, a7 = 0.f;
  float d0 = 0.f, d1 = 0.f, d2 = 0.f, d3 = 0.f;

  for (int base = start; base < end; base += 16) {
    int cnt = min(16, end - base);
    if (p < cnt) {
      int s = csr_src[base + p];
      float4 as = *(const float4*)&asrc0[(size_t)s * 4];
      float w0 = __expf(lrelu(as.x + ad.x));
      float w1 = __expf(lrelu(as.y + ad.y));
      float w2 = __expf(lrelu(as.z + ad.z));
      float w3 = __expf(lrelu(as.w + ad.w));
      d0 += w0; d1 += w1; d2 += w2; d3 += w3;
      ss[grp][p] = s;
      ws[grp][0][p] = w0;
      ws[grp][1][p] = w1;
      ws[grp][2][p] = w2;
      ws[grp][3][p] = w3;
    }
    __builtin_amdgcn_wave_barrier();
    if (cnt == 16) {
      // full chunk: 16 independent gathers in flight
      uint4 hv[16];
#pragma unroll
      for (int e = 0; e < 16; e++) {
        int s = ss[grp][e];
        hv[e] = *(const uint4*)&h0b[(size_t)s * 64 + p * 4];
      }
#pragma unroll
      for (int e = 0; e < 16; e++) {
        float w = ws[grp][head][e];
        a0 += w * bf16_lo(hv[e].x); a1 += w * bf16_hi(hv[e].x);
        a2 += w * bf16_lo(hv[e].y); a3 += w * bf16_hi(hv[e].y);
        a4 += w * bf16_lo(hv[e].z); a5 += w * bf16_hi(hv[e].z);
        a6 += w * bf16_lo(hv[e].w); a7 += w * bf16_hi(hv[e].w);
      }
    } else {
      for (int eb = 0; eb < cnt; eb += 4) {
        int e0 = eb, e1 = eb + 1, e2 = eb + 2, e3 = eb + 3;
        float w0 = ws[grp][head][e0];
        float w1 = (e1 < cnt) ? ws[grp][head][e1] : 0.f;
        float w2 = (e2 < cnt) ? ws[grp][head][e2] : 0.f;
        float w3 = (e3 < cnt) ? ws[grp][head][e3] : 0.f;
        int s0 = ss[grp][e0];
        int s1 = ss[grp][(e1 < cnt) ? e1 : e0];
        int s2 = ss[grp][(e2 < cnt) ? e2 : e0];
        int s3 = ss[grp][(e3 < cnt) ? e3 : e0];
        uint4 h0v = *(const uint4*)&h0b[(size_t)s0 * 64 + p * 4];
        uint4 h1v = *(const uint4*)&h0b[(size_t)s1 * 64 + p * 4];
        uint4 h2v = *(const uint4*)&h0b[(size_t)s2 * 64 + p * 4];
        uint4 h3v = *(const uint4*)&h0b[(size_t)s3 * 64 + p * 4];
        a0 += w0 * bf16_lo(h0v.x); a1 += w0 * bf16_hi(h0v.x);
        a2 += w0 * bf16_lo(h0v.y); a3 += w0 * bf16_hi(h0v.y);
        a4 += w0 * bf16_lo(h0v.z); a5 += w0 * bf16_hi(h0v.z);
        a6 += w0 * bf16_lo(h0v.w); a7 += w0 * bf16_hi(h0v.w);
        a0 += w1 * bf16_lo(h1v.x); a1 += w1 * bf16_hi(h1v.x);
        a2 += w1 * bf16_lo(h1v.y); a3 += w1 * bf16_hi(h1v.y);
        a4 += w1 * bf16_lo(h1v.z); a5 += w1 * bf16_hi(h1v.z);
        a6 += w1 * bf16_lo(h1v.w); a7 += w1 * bf16_hi(h1v.w);
        a0 += w2 * bf16_lo(h2v.x); a1 += w2 * bf16_hi(h2v.x);
        a2 += w2 * bf16_lo(h2v.y); a3 += w2 * bf16_hi(h2v.y);
        a4 += w2 * bf16_lo(h2v.z); a5 += w2 * bf16_hi(h2v.z);
        a6 += w2 * bf16_lo(h2v.w); a7 += w2 * bf16_hi(h2v.w);
        a0 += w3 * bf16_lo(h3v.x); a1 += w3 * bf16_hi(h3v.x);
        a2 += w3 * bf16_lo(h3v.y); a3 += w3 * bf16_hi(h3v.y);
        a4 += w3 * bf16_lo(h3v.z); a5 += w3 * bf16_hi(h3v.z);
        a6 += w3 * bf16_lo(h3v.w); a7 += w3 * bf16_hi(h3v.w);
      }
    }
    __builtin_amdgcn_wave_barrier();
  }
#pragma unroll
  for (int mk = 1; mk < 16; mk <<= 1) {
    d0 += __shfl_xor(d0, mk);
    d1 += __shfl_xor(d1, mk);
    d2 += __shfl_xor(d2, mk);
    d3 += __shfl_xor(d3, mk);
  }
  float dh = head == 0 ? d0 : head == 1 ? d1 : head == 2 ? d2 : d3;
  float rd = 1.f / dh;
  int c = p * 8;
  float4 b1v = *(const float4*)&b0[c];
  float4 b2v = *(const float4*)&b0[c + 4];
  float o0 = a0 * rd + b1v.x, o1 = a1 * rd + b1v.y;
  float o2 = a2 * rd + b1v.z, o3 = a3 * rd + b1v.w;
  float o4 = a4 * rd + b2v.x, o5 = a5 * rd + b2v.y;
  float o6 = a6 * rd + b2v.z, o7 = a7 * rd + b2v.w;
  uint4 o;
  o.x = pack_bf16(o0, o1);
  o.y = pack_bf16(o2, o3);
  o.z = pack_bf16(o4, o5);
  o.w = pack_bf16(o6, o7);
  *(uint4*)&agg0b[(size_t)n * 64 + p * 4] = o;
}

// ---------------- BatchNorm stats (bf16 input) / finalize ----------------
__global__ __launch_bounds__(256) void bnstats_kernel(const unsigned* __restrict__ agg0b,
                                                      float* __restrict__ bnsum,
                                                      float* __restrict__ bnsq) {
  int t = threadIdx.x;
  int c2 = t & 63;
  int rg = t >> 6;
  float sl = 0.f, sh = 0.f, ql = 0.f, qh = 0.f;
  for (int r = blockIdx.x * 4 + rg; r < NN; r += 2048) {
    unsigned u = agg0b[(size_t)r * 64 + c2];
    float lo = bf16_lo(u), hi = bf16_hi(u);
    sl += lo; sh += hi;
    ql += lo * lo; qh += hi * hi;
  }
  __shared__ float L1[256], L2[256], L3[256], L4[256];
  L1[t] = sl; L2[t] = sh; L3[t] = ql; L4[t] = qh;
  __syncthreads();
  if (t < 64) {
    sl = L1[t] + L1[t + 64] + L1[t + 128] + L1[t + 192];
    sh = L2[t] + L2[t + 64] + L2[t + 128] + L2[t + 192];
    ql = L3[t] + L3[t + 64] + L3[t + 128] + L3[t + 192];
    qh = L4[t] + L4[t + 64] + L4[t + 128] + L4[t + 192];
    atomicAdd(&bnsum[2 * t], sl);
    atomicAdd(&bnsum[2 * t + 1], sh);
    atomicAdd(&bnsq[2 * t], ql);
    atomicAdd(&bnsq[2 * t + 1], qh);
  }
}

__global__ void bnfinal_kernel(const float* __restrict__ bnsum, const float* __restrict__ bnsq,
                               const float* __restrict__ gamma, const float* __restrict__ beta,
                               float* __restrict__ bnscale, float* __restrict__ bnshift) {
  int c = threadIdx.x;  // 128 threads
  float mu = bnsum[c] / (float)NN;
  float var = bnsq[c] / (float)NN - mu * mu;
  float sc = gamma[c] / sqrtf(var + BNEPS);
  bnscale[c] = sc;
  bnshift[c] = beta[c] - mu * sc;
}

// ---- GEMM1 via MFMA: bf16 input + fused BN+ELU, alpha1 epilogue, bf16 h1 ----
__global__ __launch_bounds__(256) void gemm1_kernel(const unsigned* __restrict__ agg0b,
                                                    const float* __restrict__ bnscale,
                                                    const float* __restrict__ bnshift,
                                                    const float* __restrict__ W1,
                                                    const float* __restrict__ a_src1,
                                                    const float* __restrict__ a_dst1,
                                                    unsigned* __restrict__ h1b,
                                                    float* __restrict__ asrc1,
                                                    float* __restrict__ adst1) {
  __shared__ __align__(16) unsigned As[64][68];
  __shared__ __align__(16) unsigned Wt[48][68];
  int t = threadIdx.x;
  int rowbase = blockIdx.x * 64;

  for (int idx = t; idx < 48 * 64; idx += 256) {
    int c = idx >> 6, kp = idx & 63;
    float lo = (c < OD) ? W1[(size_t)(2 * kp) * OD + c] : 0.f;
    float hi = (c < OD) ? W1[(size_t)(2 * kp + 1) * OD + c] : 0.f;
    Wt[c][kp] = pack_bf16(lo, hi);
  }
  for (int idx = t; idx < 64 * 16; idx += 256) {
    int row = idx >> 4, c4 = idx & 15;
    int r = rowbase + row;
    int rc = r < NN ? r : NN - 1;
    int k = c4 * 8;
    uint4 hv = *(const uint4*)&agg0b[(size_t)rc * 64 + c4 * 4];
    float4 sc1 = *(const float4*)&bnscale[k];
    float4 sc2 = *(const float4*)&bnscale[k + 4];
    float4 sh1 = *(const float4*)&bnshift[k];
    float4 sh2 = *(const float4*)&bnshift[k + 4];
    float y0 = bf16_lo(hv.x) * sc1.x + sh1.x;
    float y1 = bf16_hi(hv.x) * sc1.y + sh1.y;
    float y2 = bf16_lo(hv.y) * sc1.z + sh1.z;
    float y3 = bf16_hi(hv.y) * sc1.w + sh1.w;
    float y4 = bf16_lo(hv.z) * sc2.x + sh2.x;
    float y5 = bf16_hi(hv.z) * sc2.y + sh2.y;
    float y6 = bf16_lo(hv.w) * sc2.z + sh2.z;
    float y7 = bf16_hi(hv.w) * sc2.w + sh2.w;
    y0 = y0 > 0.f ? y0 : expm1f(y0);
    y1 = y1 > 0.f ? y1 : expm1f(y1);
    y2 = y2 > 0.f ? y2 : expm1f(y2);
    y3 = y3 > 0.f ? y3 : expm1f(y3);
    y4 = y4 > 0.f ? y4 : expm1f(y4);
    y5 = y5 > 0.f ? y5 : expm1f(y5);
    y6 = y6 > 0.f ? y6 : expm1f(y6);
    y7 = y7 > 0.f ? y7 : expm1f(y7);
    As[row][c4 * 4 + 0] = pack_bf16(y0, y1);
    As[row][c4 * 4 + 1] = pack_bf16(y2, y3);
    As[row][c4 * 4 + 2] = pack_bf16(y4, y5);
    As[row][c4 * 4 + 3] = pack_bf16(y6, y7);
  }
  __syncthreads();

  int lane = t & 63, w = t >> 6;
  int mrow = lane & 15, g = lane >> 4;
  f32x4 acc0 = {0.f, 0.f, 0.f, 0.f};
  f32x4 acc1 = {0.f, 0.f, 0.f, 0.f};
  f32x4 acc2 = {0.f, 0.f, 0.f, 0.f};
#pragma unroll
  for (int ks = 0; ks < 4; ks++) {
    bf16x8 a = *(const bf16x8*)&As[w * 16 + mrow][ks * 16 + g * 4];
    bf16x8 b0v = *(const bf16x8*)&Wt[mrow][ks * 16 + g * 4];
    bf16x8 b1v = *(const bf16x8*)&Wt[16 + mrow][ks * 16 + g * 4];
    bf16x8 b2v = *(const bf16x8*)&Wt[32 + mrow][ks * 16 + g * 4];
    acc0 = __builtin_amdgcn_mfma_f32_16x16x32_bf16(a, b0v, acc0, 0, 0, 0);
    acc1 = __builtin_amdgcn_mfma_f32_16x16x32_bf16(a, b1v, acc1, 0, 0, 0);
    acc2 = __builtin_amdgcn_mfma_f32_16x16x32_bf16(a, b2v, acc2, 0, 0, 0);
  }
  int col = lane & 15;
  float as0 = (col < OD)      ? a_src1[col]      : 0.f;
  float as1 = (16 + col < OD) ? a_src1[16 + col] : 0.f;
  float as2 = (32 + col < OD) ? a_src1[32 + col] : 0.f;
  float ad0 = (col < OD)      ? a_dst1[col]      : 0.f;
  float ad1 = (16 + col < OD) ? a_dst1[16 + col] : 0.f;
  float ad2 = (32 + col < OD) ? a_dst1[32 + col] : 0.f;
#pragma unroll
  for (int reg = 0; reg < 4; reg++) {
    int r = rowbase + w * 16 + g * 4 + reg;
    float v0 = acc0[reg], v1 = acc1[reg], v2 = acc2[reg];
    float ps = v0 * as0 + v1 * as1 + v2 * as2;
    float pd = v0 * ad0 + v1 * ad1 + v2 * ad2;
#pragma unroll
    for (int mk = 1; mk < 16; mk <<= 1) { ps += __shfl_xor(ps, mk); pd += __shfl_xor(pd, mk); }
    bool rok = r < NN;
    if ((lane & 15) == 0 && rok) { asrc1[r] = ps; adst1[r] = pd; }
    float n0 = __shfl_xor(v0, 1), n1 = __shfl_xor(v1, 1), n2 = __shfl_xor(v2, 1);
    if (!(col & 1) && rok) {
      h1b[(size_t)r * 20 + ((col) >> 1)]      = pack_bf16(v0, n0);
      h1b[(size_t)r * 20 + ((16 + col) >> 1)] = pack_bf16(v1, n1);
      if (32 + col < OD) h1b[(size_t)r * 20 + ((32 + col) >> 1)] = pack_bf16(v2, n2);
    }
  }
}

// ---- layer-1 aggregate: one wave/node; 4-deep inner pipeline ----
__global__ __launch_bounds__(256) void agg1_kernel(const int* __restrict__ csr_src,
                                                   const int* __restrict__ rowptr,
                                                   const float* __restrict__ asrc1,
                                                   const float* __restrict__ adst1,
                                                   const unsigned* __restrict__ h1b,
                                                   const float* __restrict__ b1,
                                                   float* __restrict__ out) {
  __shared__ float ws[4][64];
  __shared__ int   ss[4][64];
  int t = threadIdx.x;
  int lane = t & 63, wv = t >> 6;
  int n = blockIdx.x * 4 + wv;
  if (n >= NN) return;
  int start = rowptr[n], end = rowptr[n + 1];
  float ad = adst1[n];
  int esub = lane / 20;        // 0..2 for lanes 0..59
  int chan = lane - esub * 20;
  float dsum = 0.f, acc0 = 0.f, acc1 = 0.f;
  for (int base = start; base < end; base += 64) {
    int cnt = min(64, end - base);
    if (lane < cnt) {
      int s = csr_src[base + lane];
      float w = __expf(lrelu(asrc1[s] + ad));
      dsum += w;
      ss[wv][lane] = s;
      ws[wv][lane] = w;
    }
    __builtin_amdgcn_wave_barrier();
    if (lane < 60) {
      int e = esub;
      for (; e + 9 < cnt; e += 12) {
        int s0 = ss[wv][e], s1 = ss[wv][e + 3], s2 = ss[wv][e + 6], s3 = ss[wv][e + 9];
        unsigned u0 = h1b[(size_t)s0 * 20 + chan];
        unsigned u1 = h1b[(size_t)s1 * 20 + chan];
        unsigned u2 = h1b[(size_t)s2 * 20 + chan];
        unsigned u3 = h1b[(size_t)s3 * 20 + chan];
        float w0 = ws[wv][e], w1 = ws[wv][e + 3], w2 = ws[wv][e + 6], w3 = ws[wv][e + 9];
        acc0 += w0 * bf16_lo(u0); acc1 += w0 * bf16_hi(u0);
        acc0 += w1 * bf16_lo(u1); acc1 += w1 * bf16_hi(u1);
        acc0 += w2 * bf16_lo(u2); acc1 += w2 * bf16_hi(u2);
        acc0 += w3 * bf16_lo(u3); acc1 += w3 * bf16_hi(u3);
      }
      for (; e < cnt; e += 3) {
        int s = ss[wv][e];
        float w = ws[wv][e];
        unsigned hv = h1b[(size_t)s * 20 + chan];
        acc0 += w * bf16_lo(hv);
        acc1 += w * bf16_hi(hv);
      }
    }
    __builtin_amdgcn_wave_barrier();
  }
#pragma unroll
  for (int mk = 1; mk < 64; mk <<= 1) dsum += __shfl_xor(dsum, mk);
  float rd = 1.f / dsum;
  float b0v = __shfl(acc0, lane + 20);
  float c0v = __shfl(acc0, lane + 40);
  float b1v = __shfl(acc1, lane + 20);
  float c1v = __shfl(acc1, lane + 40);
  if (lane < 20) {
    float2 o;
    o.x = (acc0 + b0v + c0v) * rd + b1[lane * 2];
    o.y = (acc1 + b1v + c1v) * rd + b1[lane * 2 + 1];
    *(float2*)&out[(size_t)n * 40 + lane * 2] = o;
  }
}

// ---------------- host launch ----------------
extern "C" void kernel_launch(void* const* d_in, const int* in_sizes, int n_in,
                              void* d_out, int out_size, void* d_ws, size_t ws_size,
                              hipStream_t stream) {
  const float* x       = (const float*)d_in[0];
  const int*   ei      = (const int*)d_in[1];
  const float* W0      = (const float*)d_in[2];
  const float* a_src0  = (const float*)d_in[3];
  const float* a_dst0  = (const float*)d_in[4];
  const float* b0      = (const float*)d_in[5];
  const float* gamma0  = (const float*)d_in[6];
  const float* beta0   = (const float*)d_in[7];
  const float* W1      = (const float*)d_in[8];
  const float* a_src1  = (const float*)d_in[9];
  const float* a_dst1  = (const float*)d_in[10];
  const float* b1      = (const float*)d_in[11];
  float* out = (float*)d_out;

  char* ws = (char*)d_ws;
  size_t off = 0;
  auto alloc = [&](size_t bytes) {
    void* p = ws + off;
    off += (bytes + 255) & ~(size_t)255;
    return p;
  };
  // zero-region first: deg, bnsum, bnsq (contiguous)
  int*   deg      = (int*)alloc((size_t)NN * 4);
  float* bnsum    = (float*)alloc(128 * 4);
  float* bnsq     = (float*)alloc(128 * 4);
  unsigned* h0b   = (unsigned*)alloc((size_t)NN * 64 * 4);   // bf16x2
  unsigned* agg0b = (unsigned*)alloc((size_t)NN * 64 * 4);   // bf16x2
  unsigned* h1b   = (unsigned*)alloc((size_t)NN * 20 * 4);   // bf16x2
  float* asrc0    = (float*)alloc((size_t)NN * 4 * 4);
  float* adst0    = (float*)alloc((size_t)NN * 4 * 4);
  float* asrc1    = (float*)alloc((size_t)NN * 4);
  float* adst1    = (float*)alloc((size_t)NN * 4);
  float* bnscale  = (float*)alloc(128 * 4);
  float* bnshift  = (float*)alloc(128 * 4);
  int*   rowptr   = (int*)alloc((size_t)(NN + 1) * 4);
  int*   scanned  = (int*)alloc((size_t)NN * 4);
  int*   csr      = (int*)alloc((size_t)ETOT * 4);
  int*   rank     = (int*)alloc((size_t)ETOT * 4);
  int*   bsums    = (int*)alloc(512 * 4);
  unsigned* w0t   = (unsigned*)alloc(128 * 64 * 4);
  (void)ws_size; (void)in_sizes; (void)n_in; (void)out_size;

  size_t zbytes = (char*)(bnsq + 128) - (char*)deg;
  hipMemsetAsync(deg, 0, zbytes, stream);

  const int NB = (NN + 255) / 256;
  const int egrid = (ETOT + 255) / 256;

  w0pack_kernel<<<32, 256, 0, stream>>>(W0, w0t);
  gemm0_kernel<<<(NN + 63) / 64, 256, 0, stream>>>(x, w0t, a_src0, a_dst0, h0b, asrc0, adst0,
                                                   ei, deg, rank);
  scanA_kernel<<<NB, 256, 0, stream>>>(deg, scanned, bsums);
  scanB_kernel<<<1, 512, 0, stream>>>(bsums, NB);
  scanC_kernel<<<NB, 256, 0, stream>>>(scanned, deg, bsums, rowptr);
  scatter_kernel<<<egrid, 256, 0, stream>>>(ei, rowptr, rank, csr);
  agg0_kernel<<<(NN + 15) / 16, 256, 0, stream>>>(csr, rowptr, asrc0, adst0, h0b, b0, agg0b);
  bnstats_kernel<<<512, 256, 0, stream>>>(agg0b, bnsum, bnsq);
  bnfinal_kernel<<<1, 128, 0, stream>>>(bnsum, bnsq, gamma0, beta0, bnscale, bnshift);
  gemm1_kernel<<<(NN + 63) / 64, 256, 0, stream>>>(agg0b, bnscale, bnshift, W1, a_src1, a_dst1,
                                                   h1b, asrc1, adst1);
  agg1_kernel<<<(NN + 3) / 4, 256, 0, stream>>>(csr, rowptr, asrc1, adst1, h1b, b1, out);
}